// Round 1
// baseline (2296.358 us; speedup 1.0000x reference)
//
#include <hip/hip_runtime.h>
#include <hip/hip_bf16.h>
#include <math.h>

// Problem: sparse multi-head attention (GAT-style).
// N nodes, E edges, IN=OUT=512, H=8 heads, D=64 head_dim.
// Layout decision: q/k/v stored head-transposed [H][N][64] so each head's
// 64-dim vector is contiguous (256B) for edge gathers.

#define IN_DIM 512
#define OUT_DIM 512
#define NHEAD 8
#define HDIM 64

// ---------------- QKV GEMM (fp32, 128x128 tile, LDS-staged) ----------------
__global__ __launch_bounds__(256) void qkv_gemm(
    const float* __restrict__ Hm, const float* __restrict__ Wq, const float* __restrict__ bq,
    const float* __restrict__ Wk, const float* __restrict__ bk,
    const float* __restrict__ Wv, const float* __restrict__ bv,
    float* __restrict__ qT, float* __restrict__ kT, float* __restrict__ vT, int Nn) {
  __shared__ float As[16][128];
  __shared__ float Bs[16][128];
  const int tid = threadIdx.x;
  const int mtile = blockIdx.x;
  const int yt = blockIdx.y;           // 0..11 : 4 column-tiles per matrix x 3 matrices
  const int mat = yt >> 2;             // 0=q 1=k 2=v
  const int ctile = yt & 3;
  const float* W    = (mat == 0) ? Wq : (mat == 1) ? Wk : Wv;
  const float* bias = (mat == 0) ? bq : (mat == 1) ? bk : bv;
  float* dst        = (mat == 0) ? qT : (mat == 1) ? kT : vT;
  const int row0 = mtile * 128;
  const int col0 = ctile * 128;
  const int tr = tid >> 4, tc = tid & 15;      // 16x16 thread grid, 8x8 micro-tile
  const int ar = tid >> 2;                     // 0..63
  const int ak = (tid & 3) * 4;
  const int bkr = tid >> 5;                    // 0..7
  const int bc = (tid & 31) * 4;
  float acc[8][8];
  #pragma unroll
  for (int i = 0; i < 8; ++i)
    #pragma unroll
    for (int j = 0; j < 8; ++j) acc[i][j] = 0.f;

  for (int k0 = 0; k0 < IN_DIM; k0 += 16) {
    float4 a0 = make_float4(0,0,0,0), a1 = make_float4(0,0,0,0);
    const int r0 = row0 + ar, r1 = row0 + ar + 64;
    if (r0 < Nn) a0 = *(const float4*)(Hm + (size_t)r0 * IN_DIM + k0 + ak);
    if (r1 < Nn) a1 = *(const float4*)(Hm + (size_t)r1 * IN_DIM + k0 + ak);
    const float4 b0 = *(const float4*)(W + (size_t)(k0 + bkr) * OUT_DIM + col0 + bc);
    const float4 b1 = *(const float4*)(W + (size_t)(k0 + bkr + 8) * OUT_DIM + col0 + bc);
    __syncthreads();
    As[ak+0][ar] = a0.x; As[ak+1][ar] = a0.y; As[ak+2][ar] = a0.z; As[ak+3][ar] = a0.w;
    As[ak+0][ar+64] = a1.x; As[ak+1][ar+64] = a1.y; As[ak+2][ar+64] = a1.z; As[ak+3][ar+64] = a1.w;
    *(float4*)&Bs[bkr][bc] = b0;
    *(float4*)&Bs[bkr+8][bc] = b1;
    __syncthreads();
    #pragma unroll
    for (int kk = 0; kk < 16; ++kk) {
      const float4 av0 = *(const float4*)&As[kk][tr*8];
      const float4 av1 = *(const float4*)&As[kk][tr*8+4];
      const float4 bv0 = *(const float4*)&Bs[kk][tc*8];
      const float4 bv1 = *(const float4*)&Bs[kk][tc*8+4];
      const float a[8] = {av0.x,av0.y,av0.z,av0.w,av1.x,av1.y,av1.z,av1.w};
      const float b[8] = {bv0.x,bv0.y,bv0.z,bv0.w,bv1.x,bv1.y,bv1.z,bv1.w};
      #pragma unroll
      for (int i = 0; i < 8; ++i)
        #pragma unroll
        for (int j = 0; j < 8; ++j) acc[i][j] = fmaf(a[i], b[j], acc[i][j]);
    }
  }
  const float scale = (mat == 0) ? 0.125f : 1.0f;   // D^-0.5 = 1/8 on q only
  #pragma unroll
  for (int i = 0; i < 8; ++i) {
    const int r = row0 + tr*8 + i;
    if (r >= Nn) continue;
    #pragma unroll
    for (int j = 0; j < 8; ++j) {
      const int cc = col0 + tc*8 + j;          // 0..511 ; d = cc>>3, h = cc&7
      const float val = (acc[i][j] + bias[cc]) * scale;
      dst[(size_t)(cc & 7) * (size_t)Nn * HDIM + (size_t)r * HDIM + (cc >> 3)] = val;
    }
  }
}

// ---------------- CSR build ----------------
__global__ void hist_kernel(const int* __restrict__ row, int* __restrict__ counts, int E_) {
  const int i = blockIdx.x * blockDim.x + threadIdx.x;
  if (i < E_) atomicAdd(&counts[row[i]], 1);
}

__global__ __launch_bounds__(1024) void scan_kernel(const int* __restrict__ counts,
                                                    int* __restrict__ offsets,
                                                    int* __restrict__ cursor, int n) {
  __shared__ int lds[1024];
  __shared__ int running_s;
  const int t = threadIdx.x;
  if (t == 0) running_s = 0;
  __syncthreads();
  for (int base = 0; base < n; base += 1024) {
    const int i = base + t;
    const int c = (i < n) ? counts[i] : 0;
    lds[t] = c;
    __syncthreads();
    int val = c;
    for (int off = 1; off < 1024; off <<= 1) {
      const int add = (t >= off) ? lds[t - off] : 0;
      __syncthreads();
      val += add;
      lds[t] = val;
      __syncthreads();
    }
    const int running = running_s;
    if (i < n) { const int ex = running + val - c; offsets[i] = ex; cursor[i] = ex; }
    __syncthreads();
    if (t == 1023) running_s = running + val;
    __syncthreads();
  }
  if (t == 0) offsets[n] = running_s;
}

__global__ void scatter_kernel(const int* __restrict__ row, const int* __restrict__ col,
                               int* __restrict__ cursor, int* __restrict__ rowsorted,
                               int* __restrict__ colsorted, int E_) {
  const int i = blockIdx.x * blockDim.x + threadIdx.x;
  if (i < E_) {
    const int r = row[i];
    const int pos = atomicAdd(&cursor[r], 1);
    rowsorted[pos] = r;
    colsorted[pos] = col[i];
  }
}

// ---------------- bsddmm: scores[s,h] = <q[r,:,h], k[c,:,h]> (sorted order) --
__global__ __launch_bounds__(256) void bsddmm_kernel(
    const float* __restrict__ qT, const float* __restrict__ kT,
    const int* __restrict__ rowsorted, const int* __restrict__ colsorted,
    float* __restrict__ scores, int E_, int Nn) {
  const int wid = (int)((blockIdx.x * (size_t)blockDim.x + threadIdx.x) >> 6);
  if (wid >= E_) return;
  const int l = threadIdx.x & 63;
  const int hh = l >> 3;           // head
  const int j  = l & 7;            // 8-float chunk within 64-dim
  const int r = rowsorted[wid];
  const int c = colsorted[wid];
  const size_t hbase = (size_t)hh * (size_t)Nn * HDIM;
  const float4* qp = (const float4*)(qT + hbase + (size_t)r * HDIM + j * 8);
  const float4* kp = (const float4*)(kT + hbase + (size_t)c * HDIM + j * 8);
  const float4 q0 = qp[0], q1 = qp[1];
  const float4 k0 = kp[0], k1 = kp[1];
  float s = q0.x*k0.x + q0.y*k0.y + q0.z*k0.z + q0.w*k0.w
          + q1.x*k1.x + q1.y*k1.y + q1.z*k1.z + q1.w*k1.w;
  s += __shfl_xor(s, 1);
  s += __shfl_xor(s, 2);
  s += __shfl_xor(s, 4);
  if (j == 0) scores[(size_t)wid * NHEAD + hh] = s;
}

// ---------------- fused segment softmax + SPMM (one wave per node) ----------
__device__ __forceinline__ float sel8(const float v[8], int idx) {
  float r = v[0];
  r = (idx == 1) ? v[1] : r;
  r = (idx == 2) ? v[2] : r;
  r = (idx == 3) ? v[3] : r;
  r = (idx == 4) ? v[4] : r;
  r = (idx == 5) ? v[5] : r;
  r = (idx == 6) ? v[6] : r;
  r = (idx == 7) ? v[7] : r;
  return r;
}

__global__ __launch_bounds__(256) void softmax_spmm_kernel(
    const float* __restrict__ scores, const float* __restrict__ vT,
    const int* __restrict__ colsorted, const int* __restrict__ offsets,
    float* __restrict__ out, int Nn) {
  const int wid = (int)((blockIdx.x * (size_t)blockDim.x + threadIdx.x) >> 6);
  if (wid >= Nn) return;
  const int l = threadIdx.x & 63;
  const int hh = l >> 3;           // head this lane accumulates
  const int dg = (l & 7) * 8;      // d-block base
  const int start = offsets[wid], end = offsets[wid + 1];

  if (start == end) {              // empty segment -> zeros
    #pragma unroll
    for (int x = 0; x < 8; ++x)
      out[(size_t)wid * OUT_DIM + (size_t)(dg + x) * NHEAD + hh] = 0.f;
    return;
  }

  // Phase 1: per-head max over segment
  float m[8];
  #pragma unroll
  for (int x = 0; x < 8; ++x) m[x] = -1e30f;
  for (int s = start + l; s < end; s += 64) {
    const float4 a = *(const float4*)(scores + (size_t)s * NHEAD);
    const float4 b = *(const float4*)(scores + (size_t)s * NHEAD + 4);
    m[0] = fmaxf(m[0], a.x); m[1] = fmaxf(m[1], a.y);
    m[2] = fmaxf(m[2], a.z); m[3] = fmaxf(m[3], a.w);
    m[4] = fmaxf(m[4], b.x); m[5] = fmaxf(m[5], b.y);
    m[6] = fmaxf(m[6], b.z); m[7] = fmaxf(m[7], b.w);
  }
  #pragma unroll
  for (int off = 1; off < 64; off <<= 1) {
    #pragma unroll
    for (int x = 0; x < 8; ++x) m[x] = fmaxf(m[x], __shfl_xor(m[x], off));
  }

  // Phase 2: per-head sum of exp(s - m)
  float dsum[8];
  #pragma unroll
  for (int x = 0; x < 8; ++x) dsum[x] = 0.f;
  for (int s = start + l; s < end; s += 64) {
    const float4 a = *(const float4*)(scores + (size_t)s * NHEAD);
    const float4 b = *(const float4*)(scores + (size_t)s * NHEAD + 4);
    dsum[0] += __expf(a.x - m[0]); dsum[1] += __expf(a.y - m[1]);
    dsum[2] += __expf(a.z - m[2]); dsum[3] += __expf(a.w - m[3]);
    dsum[4] += __expf(b.x - m[4]); dsum[5] += __expf(b.y - m[5]);
    dsum[6] += __expf(b.z - m[6]); dsum[7] += __expf(b.w - m[7]);
  }
  #pragma unroll
  for (int off = 1; off < 64; off <<= 1) {
    #pragma unroll
    for (int x = 0; x < 8; ++x) dsum[x] += __shfl_xor(dsum[x], off);
  }

  const float mh  = sel8(m, hh);
  const float inv = 1.0f / sel8(dsum, hh);

  // Phase 3: out[i,:,:] += exp(s-m)/denom * v[col]; lanes: h=l/8, d-block=l%8
  float acc[8];
  #pragma unroll
  for (int x = 0; x < 8; ++x) acc[x] = 0.f;
  const size_t vb = (size_t)hh * (size_t)Nn * HDIM;
  for (int s = start; s < end; ++s) {
    const int c = colsorted[s];
    const float ex = __expf(scores[(size_t)s * NHEAD + hh] - mh);
    const float4 v0 = *(const float4*)(vT + vb + (size_t)c * HDIM + dg);
    const float4 v1 = *(const float4*)(vT + vb + (size_t)c * HDIM + dg + 4);
    acc[0] = fmaf(ex, v0.x, acc[0]); acc[1] = fmaf(ex, v0.y, acc[1]);
    acc[2] = fmaf(ex, v0.z, acc[2]); acc[3] = fmaf(ex, v0.w, acc[3]);
    acc[4] = fmaf(ex, v1.x, acc[4]); acc[5] = fmaf(ex, v1.y, acc[5]);
    acc[6] = fmaf(ex, v1.z, acc[6]); acc[7] = fmaf(ex, v1.w, acc[7]);
  }
  #pragma unroll
  for (int x = 0; x < 8; ++x)
    out[(size_t)wid * OUT_DIM + (size_t)(dg + x) * NHEAD + hh] = acc[x] * inv;
}

// ---------------- launch ----------------
extern "C" void kernel_launch(void* const* d_in, const int* in_sizes, int n_in,
                              void* d_out, int out_size, void* d_ws, size_t ws_size,
                              hipStream_t stream) {
  const float* Hm = (const float*)d_in[0];
  const float* Wq = (const float*)d_in[1];
  const float* bq = (const float*)d_in[2];
  const float* Wk = (const float*)d_in[3];
  const float* bk = (const float*)d_in[4];
  const float* Wv = (const float*)d_in[5];
  const float* bv = (const float*)d_in[6];
  const int* row  = (const int*)d_in[7];
  const int* col  = (const int*)d_in[8];
  float* out = (float*)d_out;

  const int Nn = in_sizes[0] / IN_DIM;   // 50000
  const int E  = in_sizes[7];            // 1600000

  // workspace carve-up (fp32 everywhere): ~372 MB
  const size_t NQ = (size_t)Nn * OUT_DIM;
  float* qT     = (float*)d_ws;          // [H][N][64]
  float* kT     = qT + NQ;
  float* vT     = kT + NQ;
  float* scores = vT + NQ;               // [E][8] in CSR-sorted order
  int* counts    = (int*)(scores + (size_t)E * NHEAD);
  int* offsets   = counts + Nn;          // N+1
  int* cursor    = offsets + Nn + 1;
  int* rowsorted = cursor + Nn;          // E
  int* colsorted = rowsorted + E;        // E

  hipMemsetAsync(counts, 0, (size_t)Nn * sizeof(int), stream);
  hist_kernel<<<(E + 255) / 256, 256, 0, stream>>>(row, counts, E);
  scan_kernel<<<1, 1024, 0, stream>>>(counts, offsets, cursor, Nn);
  scatter_kernel<<<(E + 255) / 256, 256, 0, stream>>>(row, col, cursor, rowsorted, colsorted, E);

  dim3 ggrid((Nn + 127) / 128, 12);
  qkv_gemm<<<ggrid, 256, 0, stream>>>(Hm, Wq, bq, Wk, bk, Wv, bv, qT, kT, vT, Nn);

  const size_t ddmm_threads = (size_t)E * 64;
  bsddmm_kernel<<<(int)((ddmm_threads + 255) / 256), 256, 0, stream>>>(
      qT, kT, rowsorted, colsorted, scores, E, Nn);

  const size_t spmm_threads = (size_t)Nn * 64;
  softmax_spmm_kernel<<<(int)((spmm_threads + 255) / 256), 256, 0, stream>>>(
      scores, vT, colsorted, offsets, out, Nn);
}

// Round 2
// 1363.900 us; speedup vs baseline: 1.6837x; 1.6837x over previous
//
#include <hip/hip_runtime.h>
#include <hip/hip_bf16.h>
#include <math.h>

// Sparse multi-head attention (GAT-style). N=50000, E=1.6M, IN=OUT=512, H=8, D=64.
// Pipeline: convert h/W to bf16 -> MFMA GEMM (writes q/k/v bf16, head-transposed
// [H][N][64]) -> CSR build -> bsddmm (edge dot) -> fused segment softmax+SPMM.

#define IN_DIM 512
#define OUT_DIM 512
#define NHEAD 8
#define HDIM 64
#define BM 128
#define BN 128
#define BK 32

typedef short bf16x8 __attribute__((ext_vector_type(8)));
typedef float f32x4 __attribute__((ext_vector_type(4)));
typedef unsigned short ushort8_t __attribute__((ext_vector_type(8)));

__device__ __forceinline__ unsigned short f2bf(float f) {
  union { float f; unsigned int u; } v; v.f = f;
  unsigned int u = v.u;
  u = (u + 0x7FFF + ((u >> 16) & 1)) >> 16;   // RNE
  return (unsigned short)u;
}
__device__ __forceinline__ float bf2f(unsigned short s) {
  union { unsigned int u; float f; } v; v.u = ((unsigned int)s) << 16;
  return v.f;
}
__device__ __forceinline__ void gload_lds16(const void* g, void* l) {
  __builtin_amdgcn_global_load_lds(
      (const __attribute__((address_space(1))) unsigned int*)g,
      (__attribute__((address_space(3))) unsigned int*)l, 16, 0, 0);
}

// ---------------- fp32 -> bf16 converts ----------------
__global__ __launch_bounds__(256) void convert_h(const float* __restrict__ Hm,
                                                 unsigned short* __restrict__ hb,
                                                 int Nn) {
  const size_t base = ((size_t)blockIdx.x * blockDim.x + threadIdx.x) * 8;
  const int row = (int)(base >> 9);
  ushort8_t o = {0,0,0,0,0,0,0,0};
  if (row < Nn) {
    const float4 a = *(const float4*)(Hm + base);
    const float4 b = *(const float4*)(Hm + base + 4);
    o[0]=f2bf(a.x); o[1]=f2bf(a.y); o[2]=f2bf(a.z); o[3]=f2bf(a.w);
    o[4]=f2bf(b.x); o[5]=f2bf(b.y); o[6]=f2bf(b.z); o[7]=f2bf(b.w);
  }
  *(ushort8_t*)(hb + base) = o;
}

// Wt[mat*512 + n][k] = W_mat[k][n], bf16. LDS tile transpose 64x64.
__global__ __launch_bounds__(256) void convert_w(const float* __restrict__ Wq,
                                                 const float* __restrict__ Wk,
                                                 const float* __restrict__ Wv,
                                                 unsigned short* __restrict__ Wt) {
  __shared__ unsigned short tile[64][72];
  const int mat = blockIdx.z;
  const float* W = (mat == 0) ? Wq : (mat == 1) ? Wk : Wv;
  const int k0 = blockIdx.x * 64, n0 = blockIdx.y * 64;
  const int tid = threadIdx.x;
  const int r = tid >> 2, cb = (tid & 3) * 16;
  #pragma unroll
  for (int x = 0; x < 16; x += 4) {
    const float4 f = *(const float4*)(W + (size_t)(k0 + r) * OUT_DIM + n0 + cb + x);
    tile[cb + x + 0][r] = f2bf(f.x);
    tile[cb + x + 1][r] = f2bf(f.y);
    tile[cb + x + 2][r] = f2bf(f.z);
    tile[cb + x + 3][r] = f2bf(f.w);
  }
  __syncthreads();
  ushort8_t o1, o2;
  #pragma unroll
  for (int x = 0; x < 8; ++x) { o1[x] = tile[r][cb + x]; o2[x] = tile[r][cb + 8 + x]; }
  unsigned short* dst = Wt + (size_t)(mat * 512 + n0 + r) * IN_DIM + k0 + cb;
  *(ushort8_t*)(dst) = o1;
  *(ushort8_t*)(dst + 8) = o2;
}

// ---------------- MFMA bf16 GEMM: [Mpad,512] x [512,1536] ----------------
// A staged [128][32] bf16 in LDS with k-chunk XOR swizzle (kc ^= (row>>1)&3),
// B^T staged identically. global_load_lds width=16, pre-swizzled global source.
__global__ __launch_bounds__(256, 2) void qkv_gemm_mfma(
    const unsigned short* __restrict__ hb,   // [Mpad][512] bf16 (padded, zero tail)
    const unsigned short* __restrict__ Wt,   // [1536][512] bf16 (W^T)
    const float* __restrict__ bq, const float* __restrict__ bk, const float* __restrict__ bv,
    unsigned short* __restrict__ qTb, unsigned short* __restrict__ kTb,
    unsigned short* __restrict__ vTb, int Nn) {
  __shared__ __align__(16) unsigned short As[BM * BK];
  __shared__ __align__(16) unsigned short Bs[BN * BK];
  const int tid = threadIdx.x;
  const int l = tid & 63;
  const int w = tid >> 6;
  const int wr = w >> 1, wc = w & 1;          // wave -> 64x64 quadrant
  const int row0 = blockIdx.x * BM;
  const int col0 = blockIdx.y * BN;           // 0..1535, one matrix per block

  f32x4 acc[4][4];
  const f32x4 zero = {0.f, 0.f, 0.f, 0.f};
  #pragma unroll
  for (int m = 0; m < 4; ++m)
    #pragma unroll
    for (int n = 0; n < 4; ++n) acc[m][n] = zero;

  const int kcl = tid & 3;                    // 16B chunk slot within BK
  const int rl0 = tid >> 2;                   // tile-local row for issue 0

  for (int k0 = 0; k0 < IN_DIM; k0 += BK) {
    __syncthreads();
    #pragma unroll
    for (int t = 0; t < 2; ++t) {
      const int rl = rl0 + t * 64;
      const int kk = (kcl ^ ((rl >> 1) & 3)) * 8;   // pre-swizzled global source
      gload_lds16(hb + (size_t)(row0 + rl) * IN_DIM + k0 + kk,
                  (char*)As + t * 4096 + w * 1024);
      gload_lds16(Wt + (size_t)(col0 + rl) * IN_DIM + k0 + kk,
                  (char*)Bs + t * 4096 + w * 1024);
    }
    __syncthreads();   // drains vmcnt(0): LDS tiles ready
    bf16x8 af[4], bfr[4];
    #pragma unroll
    for (int m = 0; m < 4; ++m) {
      const int row = wr * 64 + m * 16 + (l & 15);
      const int kc = (l >> 4) ^ ((row >> 1) & 3);
      af[m] = *(const bf16x8*)&As[row * BK + kc * 8];
    }
    #pragma unroll
    for (int n = 0; n < 4; ++n) {
      const int row = wc * 64 + n * 16 + (l & 15);
      const int kc = (l >> 4) ^ ((row >> 1) & 3);
      bfr[n] = *(const bf16x8*)&Bs[row * BK + kc * 8];
    }
    #pragma unroll
    for (int m = 0; m < 4; ++m)
      #pragma unroll
      for (int n = 0; n < 4; ++n)
        acc[m][n] = __builtin_amdgcn_mfma_f32_16x16x32_bf16(af[m], bfr[n], acc[m][n], 0, 0, 0);
  }

  // epilogue: C[r][c] -> dst[mat][h][node][d], bf16. mat uniform per block.
  const int mat = col0 >> 9;
  const float scale = (mat == 0) ? 0.125f : 1.0f;   // D^-0.5 on q
  const float* bias = (mat == 0) ? bq : (mat == 1) ? bk : bv;
  unsigned short* dst = (mat == 0) ? qTb : (mat == 1) ? kTb : vTb;
  const int colbase = (col0 & 511) + wc * 64;
  #pragma unroll
  for (int n = 0; n < 4; ++n) {
    const int cc = colbase + n * 16 + (l & 15);     // 0..511
    const int d = cc >> 3, hh = cc & 7;
    const float bsv = bias[cc];
    unsigned short* dp = dst + (size_t)hh * (size_t)Nn * HDIM + d;
    #pragma unroll
    for (int m = 0; m < 4; ++m) {
      #pragma unroll
      for (int j = 0; j < 4; ++j) {
        const int r = row0 + wr * 64 + m * 16 + (l >> 4) * 4 + j;
        if (r < Nn) dp[(size_t)r * HDIM] = f2bf((acc[m][n][j] + bsv) * scale);
      }
    }
  }
}

// ---------------- CSR build ----------------
__global__ void hist_kernel(const int* __restrict__ row, int* __restrict__ counts, int E_) {
  const int i = blockIdx.x * blockDim.x + threadIdx.x;
  if (i < E_) atomicAdd(&counts[row[i]], 1);
}

__global__ __launch_bounds__(1024) void scan_kernel(const int* __restrict__ counts,
                                                    int* __restrict__ offsets,
                                                    int* __restrict__ cursor, int n) {
  __shared__ int lds[1024];
  __shared__ int running_s;
  const int t = threadIdx.x;
  if (t == 0) running_s = 0;
  __syncthreads();
  for (int base = 0; base < n; base += 1024) {
    const int i = base + t;
    const int c = (i < n) ? counts[i] : 0;
    lds[t] = c;
    __syncthreads();
    int val = c;
    for (int off = 1; off < 1024; off <<= 1) {
      const int add = (t >= off) ? lds[t - off] : 0;
      __syncthreads();
      val += add;
      lds[t] = val;
      __syncthreads();
    }
    const int running = running_s;
    if (i < n) { const int ex = running + val - c; offsets[i] = ex; cursor[i] = ex; }
    __syncthreads();
    if (t == 1023) running_s = running + val;
    __syncthreads();
  }
  if (t == 0) offsets[n] = running_s;
}

__global__ void scatter_kernel(const int* __restrict__ row, const int* __restrict__ col,
                               int* __restrict__ cursor, int* __restrict__ rowsorted,
                               int* __restrict__ colsorted, int E_) {
  const int i = blockIdx.x * blockDim.x + threadIdx.x;
  if (i < E_) {
    const int r = row[i];
    const int pos = atomicAdd(&cursor[r], 1);
    rowsorted[pos] = r;
    colsorted[pos] = col[i];
  }
}

// ---------------- bsddmm: scores[s,h] = <q[r,:,h], k[c,:,h]> (bf16 gathers) ----
__global__ __launch_bounds__(256) void bsddmm_kernel(
    const unsigned short* __restrict__ qb, const unsigned short* __restrict__ kb,
    const int* __restrict__ rowsorted, const int* __restrict__ colsorted,
    float* __restrict__ scores, int E_, int Nn) {
  const int wid = (int)((blockIdx.x * (size_t)blockDim.x + threadIdx.x) >> 6);
  if (wid >= E_) return;
  const int l = threadIdx.x & 63;
  const int hh = l >> 3;           // head
  const int j  = l & 7;            // 8-elem chunk within 64-dim
  const int r = rowsorted[wid];
  const int c = colsorted[wid];
  const size_t hbase = (size_t)hh * (size_t)Nn * HDIM;
  const ushort8_t qv = *(const ushort8_t*)(qb + hbase + (size_t)r * HDIM + j * 8);
  const ushort8_t kv = *(const ushort8_t*)(kb + hbase + (size_t)c * HDIM + j * 8);
  float s = 0.f;
  #pragma unroll
  for (int x = 0; x < 8; ++x) s = fmaf(bf2f(qv[x]), bf2f(kv[x]), s);
  s += __shfl_xor(s, 1);
  s += __shfl_xor(s, 2);
  s += __shfl_xor(s, 4);
  if (j == 0) scores[(size_t)wid * NHEAD + hh] = s;
}

// ---------------- fused segment softmax + SPMM (one wave per node) ----------
__device__ __forceinline__ float sel8(const float v[8], int idx) {
  float r = v[0];
  r = (idx == 1) ? v[1] : r;
  r = (idx == 2) ? v[2] : r;
  r = (idx == 3) ? v[3] : r;
  r = (idx == 4) ? v[4] : r;
  r = (idx == 5) ? v[5] : r;
  r = (idx == 6) ? v[6] : r;
  r = (idx == 7) ? v[7] : r;
  return r;
}

__global__ __launch_bounds__(256) void softmax_spmm_kernel(
    const float* __restrict__ scores, const unsigned short* __restrict__ vb,
    const int* __restrict__ colsorted, const int* __restrict__ offsets,
    float* __restrict__ out, int Nn) {
  const int wid = (int)((blockIdx.x * (size_t)blockDim.x + threadIdx.x) >> 6);
  if (wid >= Nn) return;
  const int l = threadIdx.x & 63;
  const int hh = l >> 3;           // head this lane accumulates
  const int dg = (l & 7) * 8;      // d-block base
  const int start = offsets[wid], end = offsets[wid + 1];

  if (start == end) {
    #pragma unroll
    for (int x = 0; x < 8; ++x)
      out[(size_t)wid * OUT_DIM + (size_t)(dg + x) * NHEAD + hh] = 0.f;
    return;
  }

  // Phase 1: per-head max
  float m[8];
  #pragma unroll
  for (int x = 0; x < 8; ++x) m[x] = -1e30f;
  for (int s = start + l; s < end; s += 64) {
    const float4 a = *(const float4*)(scores + (size_t)s * NHEAD);
    const float4 b = *(const float4*)(scores + (size_t)s * NHEAD + 4);
    m[0] = fmaxf(m[0], a.x); m[1] = fmaxf(m[1], a.y);
    m[2] = fmaxf(m[2], a.z); m[3] = fmaxf(m[3], a.w);
    m[4] = fmaxf(m[4], b.x); m[5] = fmaxf(m[5], b.y);
    m[6] = fmaxf(m[6], b.z); m[7] = fmaxf(m[7], b.w);
  }
  #pragma unroll
  for (int off = 1; off < 64; off <<= 1) {
    #pragma unroll
    for (int x = 0; x < 8; ++x) m[x] = fmaxf(m[x], __shfl_xor(m[x], off));
  }

  // Phase 2: per-head denom
  float dsum[8];
  #pragma unroll
  for (int x = 0; x < 8; ++x) dsum[x] = 0.f;
  for (int s = start + l; s < end; s += 64) {
    const float4 a = *(const float4*)(scores + (size_t)s * NHEAD);
    const float4 b = *(const float4*)(scores + (size_t)s * NHEAD + 4);
    dsum[0] += __expf(a.x - m[0]); dsum[1] += __expf(a.y - m[1]);
    dsum[2] += __expf(a.z - m[2]); dsum[3] += __expf(a.w - m[3]);
    dsum[4] += __expf(b.x - m[4]); dsum[5] += __expf(b.y - m[5]);
    dsum[6] += __expf(b.z - m[6]); dsum[7] += __expf(b.w - m[7]);
  }
  #pragma unroll
  for (int off = 1; off < 64; off <<= 1) {
    #pragma unroll
    for (int x = 0; x < 8; ++x) dsum[x] += __shfl_xor(dsum[x], off);
  }

  const float mh  = sel8(m, hh);
  const float inv = 1.0f / sel8(dsum, hh);

  // Phase 3: accumulate exp(s-m)*v over segment; lanes: h=l/8, d-block=l%8
  float acc[8];
  #pragma unroll
  for (int x = 0; x < 8; ++x) acc[x] = 0.f;
  const size_t vbase = (size_t)hh * (size_t)Nn * HDIM;
  for (int s = start; s < end; ++s) {
    const int c = colsorted[s];
    const float ex = __expf(scores[(size_t)s * NHEAD + hh] - mh);
    const ushort8_t vv = *(const ushort8_t*)(vb + vbase + (size_t)c * HDIM + dg);
    #pragma unroll
    for (int x = 0; x < 8; ++x) acc[x] = fmaf(ex, bf2f(vv[x]), acc[x]);
  }
  #pragma unroll
  for (int x = 0; x < 8; ++x)
    out[(size_t)wid * OUT_DIM + (size_t)(dg + x) * NHEAD + hh] = acc[x] * inv;
}

// ---------------- launch ----------------
extern "C" void kernel_launch(void* const* d_in, const int* in_sizes, int n_in,
                              void* d_out, int out_size, void* d_ws, size_t ws_size,
                              hipStream_t stream) {
  const float* Hm = (const float*)d_in[0];
  const float* Wq = (const float*)d_in[1];
  const float* bq = (const float*)d_in[2];
  const float* Wk = (const float*)d_in[3];
  const float* bk = (const float*)d_in[4];
  const float* Wv = (const float*)d_in[5];
  const float* bv = (const float*)d_in[6];
  const int* row  = (const int*)d_in[7];
  const int* col  = (const int*)d_in[8];
  float* out = (float*)d_out;

  const int Nn = in_sizes[0] / IN_DIM;               // 50000
  const int E  = in_sizes[7];                        // 1600000
  const int mtiles = (Nn + BM - 1) / BM;             // 391
  const int Mpad = mtiles * BM;                      // 50048

  // workspace carve-up (all 16B-aligned)
  unsigned short* hb  = (unsigned short*)d_ws;               // [Mpad][512] bf16
  unsigned short* Wt  = hb + (size_t)Mpad * IN_DIM;          // [1536][512] bf16
  unsigned short* qTb = Wt + (size_t)3 * 512 * IN_DIM;       // [H][N][64] bf16
  unsigned short* kTb = qTb + (size_t)Nn * OUT_DIM;
  unsigned short* vTb = kTb + (size_t)Nn * OUT_DIM;
  float* scores  = (float*)(vTb + (size_t)Nn * OUT_DIM);     // [E][8] fp32 (sorted)
  int* counts    = (int*)(scores + (size_t)E * NHEAD);
  int* offsets   = counts + Nn;                              // N+1
  int* cursor    = offsets + Nn + 1;
  int* rowsorted = cursor + Nn;                              // E
  int* colsorted = rowsorted + E;                            // E

  hipMemsetAsync(counts, 0, (size_t)Nn * sizeof(int), stream);
  hist_kernel<<<(E + 255) / 256, 256, 0, stream>>>(row, counts, E);
  scan_kernel<<<1, 1024, 0, stream>>>(counts, offsets, cursor, Nn);
  scatter_kernel<<<(E + 255) / 256, 256, 0, stream>>>(row, col, cursor, rowsorted, colsorted, E);

  const int hblocks = (int)(((size_t)Mpad * IN_DIM / 8 + 255) / 256);
  convert_h<<<hblocks, 256, 0, stream>>>(Hm, hb, Nn);
  convert_w<<<dim3(8, 8, 3), 256, 0, stream>>>(Wq, Wk, Wv, Wt);

  qkv_gemm_mfma<<<dim3(mtiles, 12), 256, 0, stream>>>(hb, Wt, bq, bk, bv,
                                                      qTb, kTb, vTb, Nn);

  const size_t ddmm_threads = (size_t)E * 64;
  bsddmm_kernel<<<(int)((ddmm_threads + 255) / 256), 256, 0, stream>>>(
      qTb, kTb, rowsorted, colsorted, scores, E, Nn);

  const size_t spmm_threads = (size_t)Nn * 64;
  softmax_spmm_kernel<<<(int)((spmm_threads + 255) / 256), 256, 0, stream>>>(
      scores, vTb, colsorted, offsets, out, Nn);
}

// Round 4
// 1129.099 us; speedup vs baseline: 2.0338x; 1.2080x over previous
//
#include <hip/hip_runtime.h>
#include <hip/hip_bf16.h>
#include <math.h>

// Sparse multi-head attention (GAT-style). N=50000, E=1.6M, IN=OUT=512, H=8, D=64.
// Layout: q/k/v bf16 in [N][H*64] (head-major within row) — produced at zero cost
// by permuting W's columns in convert_w. Node rows are 1KB contiguous -> wave
// gathers are single coalesced reads; GEMM epilogue is row-major coalesced.

#define IN_DIM 512
#define OUT_DIM 512
#define NHEAD 8
#define HDIM 64
#define BM 128
#define BN 128
#define BK 32

typedef short bf16x8 __attribute__((ext_vector_type(8)));
typedef float f32x4 __attribute__((ext_vector_type(4)));
typedef unsigned short ushort8_t __attribute__((ext_vector_type(8)));

__device__ __forceinline__ unsigned short f2bf(float f) {
  union { float f; unsigned int u; } v; v.f = f;
  unsigned int u = v.u;
  u = (u + 0x7FFF + ((u >> 16) & 1)) >> 16;   // RNE
  return (unsigned short)u;
}
__device__ __forceinline__ float bf2f(unsigned short s) {
  union { unsigned int u; float f; } v; v.u = ((unsigned int)s) << 16;
  return v.f;
}
__device__ __forceinline__ void gload_lds16(const void* g, void* l) {
  __builtin_amdgcn_global_load_lds(
      (const __attribute__((address_space(1))) unsigned int*)g,
      (__attribute__((address_space(3))) unsigned int*)l, 16, 0, 0);
}

// ---------------- fp32 -> bf16 converts ----------------
__global__ __launch_bounds__(256) void convert_h(const float* __restrict__ Hm,
                                                 unsigned short* __restrict__ hb,
                                                 int Nn) {
  const size_t base = ((size_t)blockIdx.x * blockDim.x + threadIdx.x) * 8;
  const int row = (int)(base >> 9);
  ushort8_t o = {0,0,0,0,0,0,0,0};
  if (row < Nn) {
    const float4 a = *(const float4*)(Hm + base);
    const float4 b = *(const float4*)(Hm + base + 4);
    o[0]=f2bf(a.x); o[1]=f2bf(a.y); o[2]=f2bf(a.z); o[3]=f2bf(a.w);
    o[4]=f2bf(b.x); o[5]=f2bf(b.y); o[6]=f2bf(b.z); o[7]=f2bf(b.w);
  }
  *(ushort8_t*)(hb + base) = o;
}

// Wt[mat*512 + perm(n)][k] = W_mat[k][n], bf16, perm(n) = (n&7)*64 + (n>>3).
// The permuted columns make the GEMM output land directly in [N][H][64] order.
__global__ __launch_bounds__(256) void convert_w(const float* __restrict__ Wq,
                                                 const float* __restrict__ Wk,
                                                 const float* __restrict__ Wv,
                                                 unsigned short* __restrict__ Wt) {
  __shared__ unsigned short tile[64][72];
  const int mat = blockIdx.z;
  const float* W = (mat == 0) ? Wq : (mat == 1) ? Wk : Wv;
  const int k0 = blockIdx.x * 64, n0 = blockIdx.y * 64;
  const int tid = threadIdx.x;
  const int r = tid >> 2, cb = (tid & 3) * 16;
  #pragma unroll
  for (int x = 0; x < 16; x += 4) {
    const float4 f = *(const float4*)(W + (size_t)(k0 + r) * OUT_DIM + n0 + cb + x);
    tile[cb + x + 0][r] = f2bf(f.x);
    tile[cb + x + 1][r] = f2bf(f.y);
    tile[cb + x + 2][r] = f2bf(f.z);
    tile[cb + x + 3][r] = f2bf(f.w);
  }
  __syncthreads();
  ushort8_t o1, o2;
  #pragma unroll
  for (int x = 0; x < 8; ++x) { o1[x] = tile[r][cb + x]; o2[x] = tile[r][cb + 8 + x]; }
  const int n = n0 + r;
  const int np = ((n & 7) << 6) | (n >> 3);      // permuted output column
  unsigned short* dst = Wt + (size_t)(mat * 512 + np) * IN_DIM + k0 + cb;
  *(ushort8_t*)(dst) = o1;
  *(ushort8_t*)(dst + 8) = o2;
}

// ---------------- MFMA bf16 GEMM: [Mpad,512] x [512,512] x 3 mats ----------
// grid (mtiles, 4 col-tiles); mats looped inside (A tile re-staged from L2).
__global__ __launch_bounds__(256, 2) void qkv_gemm_mfma(
    const unsigned short* __restrict__ hb,   // [Mpad][512] bf16 (zero tail)
    const unsigned short* __restrict__ Wt,   // [3*512][512] bf16 (W^T, permuted rows)
    const float* __restrict__ bq, const float* __restrict__ bk, const float* __restrict__ bv,
    unsigned short* __restrict__ qTb, unsigned short* __restrict__ kTb,
    unsigned short* __restrict__ vTb, int Nn) {
  __shared__ __align__(16) unsigned short As[BM * BK];
  __shared__ __align__(16) unsigned short Bs[BN * BK];
  const int tid = threadIdx.x;
  const int l = tid & 63;
  const int w = tid >> 6;
  const int wr = w >> 1, wc = w & 1;          // wave -> 64x64 quadrant
  const int row0 = blockIdx.x * BM;
  const int col0 = blockIdx.y * BN;           // 0..511 (permuted col space)

  const int kcl = tid & 3;                    // 16B chunk slot within BK
  const int rl0 = tid >> 2;                   // tile-local row for issue 0

  for (int mat = 0; mat < 3; ++mat) {
    const unsigned short* Bsrc = Wt + (size_t)(mat * 512 + col0) * IN_DIM;
    f32x4 acc[4][4];
    const f32x4 zero = {0.f, 0.f, 0.f, 0.f};
    #pragma unroll
    for (int m = 0; m < 4; ++m)
      #pragma unroll
      for (int n = 0; n < 4; ++n) acc[m][n] = zero;

    for (int k0 = 0; k0 < IN_DIM; k0 += BK) {
      __syncthreads();
      #pragma unroll
      for (int t = 0; t < 2; ++t) {
        const int rl = rl0 + t * 64;
        const int kk = (kcl ^ ((rl >> 1) & 3)) * 8;   // pre-swizzled global source
        gload_lds16(hb + (size_t)(row0 + rl) * IN_DIM + k0 + kk,
                    (char*)As + t * 4096 + w * 1024);
        gload_lds16(Bsrc + (size_t)rl * IN_DIM + k0 + kk,
                    (char*)Bs + t * 4096 + w * 1024);
      }
      __syncthreads();   // drains vmcnt(0): LDS tiles ready
      bf16x8 af[4], bfr[4];
      #pragma unroll
      for (int m = 0; m < 4; ++m) {
        const int row = wr * 64 + m * 16 + (l & 15);
        const int kc = (l >> 4) ^ ((row >> 1) & 3);
        af[m] = *(const bf16x8*)&As[row * BK + kc * 8];
      }
      #pragma unroll
      for (int n = 0; n < 4; ++n) {
        const int row = wc * 64 + n * 16 + (l & 15);
        const int kc = (l >> 4) ^ ((row >> 1) & 3);
        bfr[n] = *(const bf16x8*)&Bs[row * BK + kc * 8];
      }
      #pragma unroll
      for (int m = 0; m < 4; ++m)
        #pragma unroll
        for (int n = 0; n < 4; ++n)
          acc[m][n] = __builtin_amdgcn_mfma_f32_16x16x32_bf16(af[m], bfr[n], acc[m][n], 0, 0, 0);
    }

    // epilogue: rows contiguous in [N][512] (= [N][H][64]); coalesced stores.
    const float scale = (mat == 0) ? 0.125f : 1.0f;     // D^-0.5 on q
    const float* bias = (mat == 0) ? bq : (mat == 1) ? bk : bv;
    unsigned short* dst = (mat == 0) ? qTb : (mat == 1) ? kTb : vTb;
    #pragma unroll
    for (int n = 0; n < 4; ++n) {
      const int cc = col0 + wc * 64 + n * 16 + (l & 15);  // permuted col 0..511
      const int o = ((cc & 63) << 3) | (cc >> 6);         // original col for bias
      const float bsv = bias[o];
      #pragma unroll
      for (int m = 0; m < 4; ++m) {
        #pragma unroll
        for (int j = 0; j < 4; ++j) {
          const int r = row0 + wr * 64 + m * 16 + (l >> 4) * 4 + j;
          if (r < Nn) dst[(size_t)r * OUT_DIM + cc] = f2bf((acc[m][n][j] + bsv) * scale);
        }
      }
    }
  }
}

// ---------------- CSR build ----------------
__global__ void hist_kernel(const int* __restrict__ row, int* __restrict__ counts, int E_) {
  const int i = blockIdx.x * blockDim.x + threadIdx.x;
  if (i < E_) atomicAdd(&counts[row[i]], 1);
}

__global__ __launch_bounds__(1024) void scan_kernel(const int* __restrict__ counts,
                                                    int* __restrict__ offsets,
                                                    int* __restrict__ cursor, int n) {
  __shared__ int lds[1024];
  __shared__ int running_s;
  const int t = threadIdx.x;
  if (t == 0) running_s = 0;
  __syncthreads();
  for (int base = 0; base < n; base += 1024) {
    const int i = base + t;
    const int c = (i < n) ? counts[i] : 0;
    lds[t] = c;
    __syncthreads();
    int val = c;
    for (int off = 1; off < 1024; off <<= 1) {
      const int add = (t >= off) ? lds[t - off] : 0;
      __syncthreads();
      val += add;
      lds[t] = val;
      __syncthreads();
    }
    const int running = running_s;
    if (i < n) { const int ex = running + val - c; offsets[i] = ex; cursor[i] = ex; }
    __syncthreads();
    if (t == 1023) running_s = running + val;
    __syncthreads();
  }
  if (t == 0) offsets[n] = running_s;
}

__global__ void scatter_kernel(const int* __restrict__ row, const int* __restrict__ col,
                               int* __restrict__ cursor, int* __restrict__ colsorted, int E_) {
  const int i = blockIdx.x * blockDim.x + threadIdx.x;
  if (i < E_) {
    const int pos = atomicAdd(&cursor[row[i]], 1);
    colsorted[pos] = col[i];
  }
}

// ---------------- bsddmm (node-centric): one wave per dst node -------------
// Lane l: head hh=l>>3, d-chunk j=l&7. q row read once; per edge one coalesced
// 1KB k-row read; 3-step shfl reduce; online per-head max -> nodemax.
__global__ __launch_bounds__(256) void bsddmm_node(
    const unsigned short* __restrict__ qb, const unsigned short* __restrict__ kb,
    const int* __restrict__ colsorted, const int* __restrict__ offsets,
    float* __restrict__ scores, float* __restrict__ nodemax, int Nn) {
  const int wid = (int)((blockIdx.x * (size_t)blockDim.x + threadIdx.x) >> 6);
  if (wid >= Nn) return;
  const int l = threadIdx.x & 63;
  const int hh = l >> 3, j = l & 7;
  const int start = offsets[wid], end = offsets[wid + 1];
  if (start == end) return;

  const size_t loff = (size_t)l * 8;          // = hh*64 + j*8
  const ushort8_t q8 = *(const ushort8_t*)(qb + (size_t)wid * OUT_DIM + loff);
  float qf[8];
  #pragma unroll
  for (int x = 0; x < 8; ++x) qf[x] = bf2f(q8[x]);

  float m_run = -1e30f;

  for (int base = start; base < end; base += 64) {
    const int cnt = min(64, end - base);
    const int myc = (l < cnt) ? colsorted[base + l] : 0;
    int u = 0;
    for (; u + 4 <= cnt; u += 4) {
      const int c0 = __shfl(myc, u + 0);
      const int c1 = __shfl(myc, u + 1);
      const int c2 = __shfl(myc, u + 2);
      const int c3 = __shfl(myc, u + 3);
      const ushort8_t ka = *(const ushort8_t*)(kb + (size_t)c0 * OUT_DIM + loff);
      const ushort8_t kb1 = *(const ushort8_t*)(kb + (size_t)c1 * OUT_DIM + loff);
      const ushort8_t kc = *(const ushort8_t*)(kb + (size_t)c2 * OUT_DIM + loff);
      const ushort8_t kd = *(const ushort8_t*)(kb + (size_t)c3 * OUT_DIM + loff);
      float s0 = 0.f, s1 = 0.f, s2 = 0.f, s3 = 0.f;
      #pragma unroll
      for (int x = 0; x < 8; ++x) {
        s0 = fmaf(qf[x], bf2f(ka[x]), s0);
        s1 = fmaf(qf[x], bf2f(kb1[x]), s1);
        s2 = fmaf(qf[x], bf2f(kc[x]), s2);
        s3 = fmaf(qf[x], bf2f(kd[x]), s3);
      }
      s0 += __shfl_xor(s0, 1); s0 += __shfl_xor(s0, 2); s0 += __shfl_xor(s0, 4);
      s1 += __shfl_xor(s1, 1); s1 += __shfl_xor(s1, 2); s1 += __shfl_xor(s1, 4);
      s2 += __shfl_xor(s2, 1); s2 += __shfl_xor(s2, 2); s2 += __shfl_xor(s2, 4);
      s3 += __shfl_xor(s3, 1); s3 += __shfl_xor(s3, 2); s3 += __shfl_xor(s3, 4);
      m_run = fmaxf(m_run, fmaxf(fmaxf(s0, s1), fmaxf(s2, s3)));
      if (j == 0) {
        scores[(size_t)(base + u + 0) * NHEAD + hh] = s0;
        scores[(size_t)(base + u + 1) * NHEAD + hh] = s1;
        scores[(size_t)(base + u + 2) * NHEAD + hh] = s2;
        scores[(size_t)(base + u + 3) * NHEAD + hh] = s3;
      }
    }
    for (; u < cnt; ++u) {
      const int c = __shfl(myc, u);
      const ushort8_t kv = *(const ushort8_t*)(kb + (size_t)c * OUT_DIM + loff);
      float s = 0.f;
      #pragma unroll
      for (int x = 0; x < 8; ++x) s = fmaf(qf[x], bf2f(kv[x]), s);
      s += __shfl_xor(s, 1); s += __shfl_xor(s, 2); s += __shfl_xor(s, 4);
      m_run = fmaxf(m_run, s);
      if (j == 0) scores[(size_t)(base + u) * NHEAD + hh] = s;
    }
  }
  if (j == 0) nodemax[(size_t)wid * NHEAD + hh] = m_run;
}

// ---------------- fused segment softmax + SPMM (one wave per node) ----------
__device__ __forceinline__ float sel8(const float v[8], int idx) {
  float r = v[0];
  r = (idx == 1) ? v[1] : r;
  r = (idx == 2) ? v[2] : r;
  r = (idx == 3) ? v[3] : r;
  r = (idx == 4) ? v[4] : r;
  r = (idx == 5) ? v[5] : r;
  r = (idx == 6) ? v[6] : r;
  r = (idx == 7) ? v[7] : r;
  return r;
}

__global__ __launch_bounds__(256) void softmax_spmm_kernel(
    const float* __restrict__ scores, const float* __restrict__ nodemax,
    const unsigned short* __restrict__ vb,
    const int* __restrict__ colsorted, const int* __restrict__ offsets,
    float* __restrict__ out, int Nn) {
  const int wid = (int)((blockIdx.x * (size_t)blockDim.x + threadIdx.x) >> 6);
  if (wid >= Nn) return;
  const int l = threadIdx.x & 63;
  const int hh = l >> 3;           // head this lane accumulates
  const int dg = (l & 7) * 8;      // d-block base
  const int start = offsets[wid], end = offsets[wid + 1];

  if (start == end) {
    #pragma unroll
    for (int x = 0; x < 8; ++x)
      out[(size_t)wid * OUT_DIM + (size_t)(dg + x) * NHEAD + hh] = 0.f;
    return;
  }

  // per-head max from bsddmm's online tracking
  const float4 ma = *(const float4*)(nodemax + (size_t)wid * NHEAD);
  const float4 mb = *(const float4*)(nodemax + (size_t)wid * NHEAD + 4);
  const float m[8] = {ma.x, ma.y, ma.z, ma.w, mb.x, mb.y, mb.z, mb.w};

  // denom: per-head sum of exp(s - m), vectorized over lanes (stride 64)
  float dsum[8];
  #pragma unroll
  for (int x = 0; x < 8; ++x) dsum[x] = 0.f;
  for (int s = start + l; s < end; s += 64) {
    const float4 a = *(const float4*)(scores + (size_t)s * NHEAD);
    const float4 b = *(const float4*)(scores + (size_t)s * NHEAD + 4);
    dsum[0] += __expf(a.x - m[0]); dsum[1] += __expf(a.y - m[1]);
    dsum[2] += __expf(a.z - m[2]); dsum[3] += __expf(a.w - m[3]);
    dsum[4] += __expf(b.x - m[4]); dsum[5] += __expf(b.y - m[5]);
    dsum[6] += __expf(b.z - m[6]); dsum[7] += __expf(b.w - m[7]);
  }
  #pragma unroll
  for (int off = 1; off < 64; off <<= 1) {
    #pragma unroll
    for (int x = 0; x < 8; ++x) dsum[x] += __shfl_xor(dsum[x], off);
  }

  const float mh  = sel8(m, hh);
  const float inv = 1.0f / sel8(dsum, hh);

  // accumulate exp(s-m)*v ; lane l reads v-row bytes [l*16, l*16+16) (coalesced 1KB)
  float acc[8];
  #pragma unroll
  for (int x = 0; x < 8; ++x) acc[x] = 0.f;
  const size_t loff = (size_t)l * 8;
  for (int base = start; base < end; base += 64) {
    const int cnt = min(64, end - base);
    const int myc = (l < cnt) ? colsorted[base + l] : 0;
    int u = 0;
    for (; u + 4 <= cnt; u += 4) {
      const int c0 = __shfl(myc, u + 0);
      const int c1 = __shfl(myc, u + 1);
      const int c2 = __shfl(myc, u + 2);
      const int c3 = __shfl(myc, u + 3);
      const float e0 = __expf(scores[(size_t)(base + u + 0) * NHEAD + hh] - mh);
      const float e1 = __expf(scores[(size_t)(base + u + 1) * NHEAD + hh] - mh);
      const float e2 = __expf(scores[(size_t)(base + u + 2) * NHEAD + hh] - mh);
      const float e3 = __expf(scores[(size_t)(base + u + 3) * NHEAD + hh] - mh);
      const ushort8_t va = *(const ushort8_t*)(vb + (size_t)c0 * OUT_DIM + loff);
      const ushort8_t vb1 = *(const ushort8_t*)(vb + (size_t)c1 * OUT_DIM + loff);
      const ushort8_t vc = *(const ushort8_t*)(vb + (size_t)c2 * OUT_DIM + loff);
      const ushort8_t vd = *(const ushort8_t*)(vb + (size_t)c3 * OUT_DIM + loff);
      #pragma unroll
      for (int x = 0; x < 8; ++x) {
        acc[x] = fmaf(e0, bf2f(va[x]), acc[x]);
        acc[x] = fmaf(e1, bf2f(vb1[x]), acc[x]);
        acc[x] = fmaf(e2, bf2f(vc[x]), acc[x]);
        acc[x] = fmaf(e3, bf2f(vd[x]), acc[x]);
      }
    }
    for (; u < cnt; ++u) {
      const int c = __shfl(myc, u);
      const float e = __expf(scores[(size_t)(base + u) * NHEAD + hh] - mh);
      const ushort8_t vv = *(const ushort8_t*)(vb + (size_t)c * OUT_DIM + loff);
      #pragma unroll
      for (int x = 0; x < 8; ++x) acc[x] = fmaf(e, bf2f(vv[x]), acc[x]);
    }
  }
  // out natural [N][D][H]: lane holds head hh, dims dg..dg+7
  #pragma unroll
  for (int x = 0; x < 8; ++x)
    out[(size_t)wid * OUT_DIM + (size_t)(dg + x) * NHEAD + hh] = acc[x] * inv;
}

// ---------------- launch ----------------
extern "C" void kernel_launch(void* const* d_in, const int* in_sizes, int n_in,
                              void* d_out, int out_size, void* d_ws, size_t ws_size,
                              hipStream_t stream) {
  const float* Hm = (const float*)d_in[0];
  const float* Wq = (const float*)d_in[1];
  const float* bq = (const float*)d_in[2];
  const float* Wk = (const float*)d_in[3];
  const float* bk = (const float*)d_in[4];
  const float* Wv = (const float*)d_in[5];
  const float* bv = (const float*)d_in[6];
  const int* row  = (const int*)d_in[7];
  const int* col  = (const int*)d_in[8];
  float* out = (float*)d_out;

  const int Nn = in_sizes[0] / IN_DIM;               // 50000
  const int E  = in_sizes[7];                        // 1600000
  const int mtiles = (Nn + BM - 1) / BM;             // 391
  const int Mpad = mtiles * BM;                      // 50048

  // workspace carve-up (all 16B-aligned)
  unsigned short* hb  = (unsigned short*)d_ws;               // [Mpad][512] bf16
  unsigned short* Wt  = hb + (size_t)Mpad * IN_DIM;          // [1536][512] bf16 (perm)
  unsigned short* qTb = Wt + (size_t)3 * 512 * IN_DIM;       // [N][H*64] bf16
  unsigned short* kTb = qTb + (size_t)Nn * OUT_DIM;
  unsigned short* vTb = kTb + (size_t)Nn * OUT_DIM;
  float* scores   = (float*)(vTb + (size_t)Nn * OUT_DIM);    // [E][8] fp32 (sorted)
  float* nodemax  = scores + (size_t)E * NHEAD;              // [N][8]
  int* counts     = (int*)(nodemax + (size_t)Nn * NHEAD);
  int* offsets    = counts + Nn;                             // N+1
  int* cursor     = offsets + Nn + 1;
  int* colsorted  = cursor + Nn;                             // E

  hipMemsetAsync(counts, 0, (size_t)Nn * sizeof(int), stream);
  hist_kernel<<<(E + 255) / 256, 256, 0, stream>>>(row, counts, E);
  scan_kernel<<<1, 1024, 0, stream>>>(counts, offsets, cursor, Nn);
  scatter_kernel<<<(E + 255) / 256, 256, 0, stream>>>(row, col, cursor, colsorted, E);

  const int hblocks = (int)(((size_t)Mpad * IN_DIM / 8 + 255) / 256);
  convert_h<<<hblocks, 256, 0, stream>>>(Hm, hb, Nn);
  convert_w<<<dim3(8, 8, 3), 256, 0, stream>>>(Wq, Wk, Wv, Wt);

  qkv_gemm_mfma<<<dim3(mtiles, 4), 256, 0, stream>>>(hb, Wt, bq, bk, bv,
                                                     qTb, kTb, vTb, Nn);

  const size_t node_threads = (size_t)Nn * 64;
  bsddmm_node<<<(int)((node_threads + 255) / 256), 256, 0, stream>>>(
      qTb, kTb, colsorted, offsets, scores, nodemax, Nn);

  softmax_spmm_kernel<<<(int)((node_threads + 255) / 256), 256, 0, stream>>>(
      scores, nodemax, vTb, colsorted, offsets, out, Nn);
}

// Round 5
// 1049.396 us; speedup vs baseline: 2.1883x; 1.0760x over previous
//
#include <hip/hip_runtime.h>
#include <hip/hip_bf16.h>
#include <math.h>

// Sparse multi-head attention (GAT-style). N=50000, E=1.6M, IN=OUT=512, H=8, D=64.
// q/k/v bf16 in [N][H*64] rows (1KB contiguous). Round 5: fused
// bsddmm+softmax+spmm (scores in per-wave LDS, cap 128 edges w/ global
// fallback) + 3-stage parallel scan.

#define IN_DIM 512
#define OUT_DIM 512
#define NHEAD 8
#define HDIM 64
#define BM 128
#define BN 128
#define BK 32
#define SEGCAP 128

typedef short bf16x8 __attribute__((ext_vector_type(8)));
typedef float f32x4 __attribute__((ext_vector_type(4)));
typedef unsigned short ushort8_t __attribute__((ext_vector_type(8)));

__device__ __forceinline__ unsigned short f2bf(float f) {
  union { float f; unsigned int u; } v; v.f = f;
  unsigned int u = v.u;
  u = (u + 0x7FFF + ((u >> 16) & 1)) >> 16;   // RNE
  return (unsigned short)u;
}
__device__ __forceinline__ float bf2f(unsigned short s) {
  union { unsigned int u; float f; } v; v.u = ((unsigned int)s) << 16;
  return v.f;
}
__device__ __forceinline__ void gload_lds16(const void* g, void* l) {
  __builtin_amdgcn_global_load_lds(
      (const __attribute__((address_space(1))) unsigned int*)g,
      (__attribute__((address_space(3))) unsigned int*)l, 16, 0, 0);
}

// ---------------- fp32 -> bf16 converts ----------------
__global__ __launch_bounds__(256) void convert_h(const float* __restrict__ Hm,
                                                 unsigned short* __restrict__ hb,
                                                 int Nn) {
  const size_t base = ((size_t)blockIdx.x * blockDim.x + threadIdx.x) * 8;
  const int row = (int)(base >> 9);
  ushort8_t o = {0,0,0,0,0,0,0,0};
  if (row < Nn) {
    const float4 a = *(const float4*)(Hm + base);
    const float4 b = *(const float4*)(Hm + base + 4);
    o[0]=f2bf(a.x); o[1]=f2bf(a.y); o[2]=f2bf(a.z); o[3]=f2bf(a.w);
    o[4]=f2bf(b.x); o[5]=f2bf(b.y); o[6]=f2bf(b.z); o[7]=f2bf(b.w);
  }
  *(ushort8_t*)(hb + base) = o;
}

// Wt[mat*512 + perm(n)][k] = W_mat[k][n], bf16, perm(n) = (n&7)*64 + (n>>3).
__global__ __launch_bounds__(256) void convert_w(const float* __restrict__ Wq,
                                                 const float* __restrict__ Wk,
                                                 const float* __restrict__ Wv,
                                                 unsigned short* __restrict__ Wt) {
  __shared__ unsigned short tile[64][72];
  const int mat = blockIdx.z;
  const float* W = (mat == 0) ? Wq : (mat == 1) ? Wk : Wv;
  const int k0 = blockIdx.x * 64, n0 = blockIdx.y * 64;
  const int tid = threadIdx.x;
  const int r = tid >> 2, cb = (tid & 3) * 16;
  #pragma unroll
  for (int x = 0; x < 16; x += 4) {
    const float4 f = *(const float4*)(W + (size_t)(k0 + r) * OUT_DIM + n0 + cb + x);
    tile[cb + x + 0][r] = f2bf(f.x);
    tile[cb + x + 1][r] = f2bf(f.y);
    tile[cb + x + 2][r] = f2bf(f.z);
    tile[cb + x + 3][r] = f2bf(f.w);
  }
  __syncthreads();
  ushort8_t o1, o2;
  #pragma unroll
  for (int x = 0; x < 8; ++x) { o1[x] = tile[r][cb + x]; o2[x] = tile[r][cb + 8 + x]; }
  const int n = n0 + r;
  const int np = ((n & 7) << 6) | (n >> 3);      // permuted output column
  unsigned short* dst = Wt + (size_t)(mat * 512 + np) * IN_DIM + k0 + cb;
  *(ushort8_t*)(dst) = o1;
  *(ushort8_t*)(dst + 8) = o2;
}

// ---------------- MFMA bf16 GEMM: [Mpad,512] x [512,512] x 3 mats ----------
__global__ __launch_bounds__(256, 2) void qkv_gemm_mfma(
    const unsigned short* __restrict__ hb,   // [Mpad][512] bf16 (zero tail)
    const unsigned short* __restrict__ Wt,   // [3*512][512] bf16 (W^T, permuted)
    const float* __restrict__ bq, const float* __restrict__ bk, const float* __restrict__ bv,
    unsigned short* __restrict__ qTb, unsigned short* __restrict__ kTb,
    unsigned short* __restrict__ vTb, int Nn) {
  __shared__ __align__(16) unsigned short As[BM * BK];
  __shared__ __align__(16) unsigned short Bs[BN * BK];
  const int tid = threadIdx.x;
  const int l = tid & 63;
  const int w = tid >> 6;
  const int wr = w >> 1, wc = w & 1;          // wave -> 64x64 quadrant
  const int row0 = blockIdx.x * BM;
  const int col0 = blockIdx.y * BN;           // 0..511 (permuted col space)

  const int kcl = tid & 3;                    // 16B chunk slot within BK
  const int rl0 = tid >> 2;                   // tile-local row for issue 0

  for (int mat = 0; mat < 3; ++mat) {
    const unsigned short* Bsrc = Wt + (size_t)(mat * 512 + col0) * IN_DIM;
    f32x4 acc[4][4];
    const f32x4 zero = {0.f, 0.f, 0.f, 0.f};
    #pragma unroll
    for (int m = 0; m < 4; ++m)
      #pragma unroll
      for (int n = 0; n < 4; ++n) acc[m][n] = zero;

    for (int k0 = 0; k0 < IN_DIM; k0 += BK) {
      __syncthreads();
      #pragma unroll
      for (int t = 0; t < 2; ++t) {
        const int rl = rl0 + t * 64;
        const int kk = (kcl ^ ((rl >> 1) & 3)) * 8;   // pre-swizzled global source
        gload_lds16(hb + (size_t)(row0 + rl) * IN_DIM + k0 + kk,
                    (char*)As + t * 4096 + w * 1024);
        gload_lds16(Bsrc + (size_t)rl * IN_DIM + k0 + kk,
                    (char*)Bs + t * 4096 + w * 1024);
      }
      __syncthreads();   // drains vmcnt(0): LDS tiles ready
      bf16x8 af[4], bfr[4];
      #pragma unroll
      for (int m = 0; m < 4; ++m) {
        const int row = wr * 64 + m * 16 + (l & 15);
        const int kc = (l >> 4) ^ ((row >> 1) & 3);
        af[m] = *(const bf16x8*)&As[row * BK + kc * 8];
      }
      #pragma unroll
      for (int n = 0; n < 4; ++n) {
        const int row = wc * 64 + n * 16 + (l & 15);
        const int kc = (l >> 4) ^ ((row >> 1) & 3);
        bfr[n] = *(const bf16x8*)&Bs[row * BK + kc * 8];
      }
      #pragma unroll
      for (int m = 0; m < 4; ++m)
        #pragma unroll
        for (int n = 0; n < 4; ++n)
          acc[m][n] = __builtin_amdgcn_mfma_f32_16x16x32_bf16(af[m], bfr[n], acc[m][n], 0, 0, 0);
    }

    // epilogue: rows contiguous in [N][512] (= [N][H][64]); coalesced stores.
    const float scale = (mat == 0) ? 0.125f : 1.0f;     // D^-0.5 on q
    const float* bias = (mat == 0) ? bq : (mat == 1) ? bk : bv;
    unsigned short* dst = (mat == 0) ? qTb : (mat == 1) ? kTb : vTb;
    #pragma unroll
    for (int n = 0; n < 4; ++n) {
      const int cc = col0 + wc * 64 + n * 16 + (l & 15);  // permuted col 0..511
      const int o = ((cc & 63) << 3) | (cc >> 6);         // original col for bias
      const float bsv = bias[o];
      #pragma unroll
      for (int m = 0; m < 4; ++m) {
        #pragma unroll
        for (int j = 0; j < 4; ++j) {
          const int r = row0 + wr * 64 + m * 16 + (l >> 4) * 4 + j;
          if (r < Nn) dst[(size_t)r * OUT_DIM + cc] = f2bf((acc[m][n][j] + bsv) * scale);
        }
      }
    }
  }
}

// ---------------- CSR build ----------------
__global__ void hist_kernel(const int* __restrict__ row, int* __restrict__ counts, int E_) {
  const int i = blockIdx.x * blockDim.x + threadIdx.x;
  if (i < E_) atomicAdd(&counts[row[i]], 1);
}

// 3-stage scan: per-block reduce -> 1-block scan of block sums -> rescan+add.
__global__ __launch_bounds__(256) void scan_partial(const int* __restrict__ counts,
                                                    int* __restrict__ bsums, int n) {
  __shared__ int red[256];
  const int t = threadIdx.x;
  const int i = blockIdx.x * 256 + t;
  red[t] = (i < n) ? counts[i] : 0;
  __syncthreads();
  #pragma unroll
  for (int off = 128; off > 0; off >>= 1) {
    if (t < off) red[t] += red[t + off];
    __syncthreads();
  }
  if (t == 0) bsums[blockIdx.x] = red[0];
}

__global__ __launch_bounds__(1024) void scan_bsums(int* __restrict__ bsums, int nb) {
  __shared__ int lds[1024];
  const int t = threadIdx.x;
  const int v = (t < nb) ? bsums[t] : 0;
  lds[t] = v;
  __syncthreads();
  for (int off = 1; off < 1024; off <<= 1) {
    const int add = (t >= off) ? lds[t - off] : 0;
    __syncthreads();
    lds[t] += add;
    __syncthreads();
  }
  if (t < nb) bsums[t] = lds[t] - v;   // exclusive
}

__global__ __launch_bounds__(256) void scan_final(const int* __restrict__ counts,
                                                  const int* __restrict__ bsums,
                                                  int* __restrict__ offsets,
                                                  int* __restrict__ cursor,
                                                  int n, int E_) {
  __shared__ int lds[256];
  const int t = threadIdx.x;
  const int i = blockIdx.x * 256 + t;
  const int c = (i < n) ? counts[i] : 0;
  lds[t] = c;
  __syncthreads();
  for (int off = 1; off < 256; off <<= 1) {
    const int add = (t >= off) ? lds[t - off] : 0;
    __syncthreads();
    lds[t] += add;
    __syncthreads();
  }
  if (i < n) {
    const int ex = lds[t] - c + bsums[blockIdx.x];
    offsets[i] = ex;
    cursor[i] = ex;
  }
  if (blockIdx.x == 0 && t == 0) offsets[n] = E_;
}

__global__ void scatter_kernel(const int* __restrict__ row, const int* __restrict__ col,
                               int* __restrict__ cursor, int* __restrict__ colsorted, int E_) {
  const int i = blockIdx.x * blockDim.x + threadIdx.x;
  if (i < E_) {
    const int pos = atomicAdd(&cursor[row[i]], 1);
    colsorted[pos] = col[i];
  }
}

// ---------------- fused bsddmm + segment-softmax + spmm --------------------
// One wave per dst node. Lane l: head hh=l>>3, chunk j=l&7 (k-phase dot /
// v-phase d-block). scores live in per-wave LDS [SEGCAP][8]; exp computed once
// (denom pass overwrites s with ex). Col indices cached in 2 regs. Nodes with
// deg > SEGCAP (none for this graph) take a global-scores fallback.
__global__ __launch_bounds__(256) void fused_attn(
    const unsigned short* __restrict__ qb, const unsigned short* __restrict__ kb,
    const unsigned short* __restrict__ vb,
    const int* __restrict__ colsorted, const int* __restrict__ offsets,
    float* __restrict__ gscores,     // fallback only
    float* __restrict__ out, int Nn) {
  __shared__ float slds_all[4][SEGCAP * NHEAD];   // 16 KB
  const int wid = (int)((blockIdx.x * (size_t)blockDim.x + threadIdx.x) >> 6);
  if (wid >= Nn) return;
  const int l = threadIdx.x & 63;
  const int hh = l >> 3, j = l & 7;
  const int start = offsets[wid], end = offsets[wid + 1];
  const int seg = end - start;
  const size_t loff = (size_t)l * 8;
  const int dg = (l & 7) * 8;

  float acc[8];
  #pragma unroll
  for (int x = 0; x < 8; ++x) acc[x] = 0.f;
  float inv = 0.f;                      // seg==0 -> write zeros

  if (seg > 0) {
    const ushort8_t q8 = *(const ushort8_t*)(qb + (size_t)wid * OUT_DIM + loff);
    float qf[8];
    #pragma unroll
    for (int x = 0; x < 8; ++x) qf[x] = bf2f(q8[x]);

    if (seg <= SEGCAP) {
      float* slds = slds_all[threadIdx.x >> 6];
      const int myc0 = (l < seg) ? colsorted[start + l] : 0;
      const int myc1 = (64 + l < seg) ? colsorted[start + 64 + l] : 0;
      float m_run = -1e30f;

      // ---- k-phase: scores -> LDS, online max
      #pragma unroll
      for (int chunk = 0; chunk < 2; ++chunk) {
        const int base = chunk * 64;
        if (base >= seg) break;
        const int cnt = min(64, seg - base);
        const int myc = chunk ? myc1 : myc0;
        int u = 0;
        for (; u + 4 <= cnt; u += 4) {
          const int c0 = __shfl(myc, u + 0);
          const int c1 = __shfl(myc, u + 1);
          const int c2 = __shfl(myc, u + 2);
          const int c3 = __shfl(myc, u + 3);
          const ushort8_t ka = *(const ushort8_t*)(kb + (size_t)c0 * OUT_DIM + loff);
          const ushort8_t kb1 = *(const ushort8_t*)(kb + (size_t)c1 * OUT_DIM + loff);
          const ushort8_t kc = *(const ushort8_t*)(kb + (size_t)c2 * OUT_DIM + loff);
          const ushort8_t kd = *(const ushort8_t*)(kb + (size_t)c3 * OUT_DIM + loff);
          float s0 = 0.f, s1 = 0.f, s2 = 0.f, s3 = 0.f;
          #pragma unroll
          for (int x = 0; x < 8; ++x) {
            s0 = fmaf(qf[x], bf2f(ka[x]), s0);
            s1 = fmaf(qf[x], bf2f(kb1[x]), s1);
            s2 = fmaf(qf[x], bf2f(kc[x]), s2);
            s3 = fmaf(qf[x], bf2f(kd[x]), s3);
          }
          s0 += __shfl_xor(s0, 1); s0 += __shfl_xor(s0, 2); s0 += __shfl_xor(s0, 4);
          s1 += __shfl_xor(s1, 1); s1 += __shfl_xor(s1, 2); s1 += __shfl_xor(s1, 4);
          s2 += __shfl_xor(s2, 1); s2 += __shfl_xor(s2, 2); s2 += __shfl_xor(s2, 4);
          s3 += __shfl_xor(s3, 1); s3 += __shfl_xor(s3, 2); s3 += __shfl_xor(s3, 4);
          m_run = fmaxf(m_run, fmaxf(fmaxf(s0, s1), fmaxf(s2, s3)));
          if (j == 0) {
            slds[(base + u + 0) * NHEAD + hh] = s0;
            slds[(base + u + 1) * NHEAD + hh] = s1;
            slds[(base + u + 2) * NHEAD + hh] = s2;
            slds[(base + u + 3) * NHEAD + hh] = s3;
          }
        }
        for (; u < cnt; ++u) {
          const int c = __shfl(myc, u);
          const ushort8_t kv = *(const ushort8_t*)(kb + (size_t)c * OUT_DIM + loff);
          float s = 0.f;
          #pragma unroll
          for (int x = 0; x < 8; ++x) s = fmaf(qf[x], bf2f(kv[x]), s);
          s += __shfl_xor(s, 1); s += __shfl_xor(s, 2); s += __shfl_xor(s, 4);
          m_run = fmaxf(m_run, s);
          if (j == 0) slds[(base + u) * NHEAD + hh] = s;
        }
      }
      // m_run is group-uniform (post-butterfly scores are identical in-group)
      __builtin_amdgcn_wave_barrier();

      // ---- denom pass: s -> ex in place, per-head sum
      float dsum = 0.f;
      for (int u = j; u < seg; u += 8) {
        const float ex = __expf(slds[u * NHEAD + hh] - m_run);
        slds[u * NHEAD + hh] = ex;
        dsum += ex;
      }
      dsum += __shfl_xor(dsum, 1);
      dsum += __shfl_xor(dsum, 2);
      dsum += __shfl_xor(dsum, 4);
      inv = 1.0f / dsum;
      __builtin_amdgcn_wave_barrier();

      // ---- v-phase: acc += ex * v[col]
      #pragma unroll
      for (int chunk = 0; chunk < 2; ++chunk) {
        const int base = chunk * 64;
        if (base >= seg) break;
        const int cnt = min(64, seg - base);
        const int myc = chunk ? myc1 : myc0;
        int u = 0;
        for (; u + 4 <= cnt; u += 4) {
          const int c0 = __shfl(myc, u + 0);
          const int c1 = __shfl(myc, u + 1);
          const int c2 = __shfl(myc, u + 2);
          const int c3 = __shfl(myc, u + 3);
          const float e0 = slds[(base + u + 0) * NHEAD + hh];
          const float e1 = slds[(base + u + 1) * NHEAD + hh];
          const float e2 = slds[(base + u + 2) * NHEAD + hh];
          const float e3 = slds[(base + u + 3) * NHEAD + hh];
          const ushort8_t va = *(const ushort8_t*)(vb + (size_t)c0 * OUT_DIM + loff);
          const ushort8_t vb1 = *(const ushort8_t*)(vb + (size_t)c1 * OUT_DIM + loff);
          const ushort8_t vc = *(const ushort8_t*)(vb + (size_t)c2 * OUT_DIM + loff);
          const ushort8_t vd = *(const ushort8_t*)(vb + (size_t)c3 * OUT_DIM + loff);
          #pragma unroll
          for (int x = 0; x < 8; ++x) {
            acc[x] = fmaf(e0, bf2f(va[x]), acc[x]);
            acc[x] = fmaf(e1, bf2f(vb1[x]), acc[x]);
            acc[x] = fmaf(e2, bf2f(vc[x]), acc[x]);
            acc[x] = fmaf(e3, bf2f(vd[x]), acc[x]);
          }
        }
        for (; u < cnt; ++u) {
          const int c = __shfl(myc, u);
          const float e = slds[(base + u) * NHEAD + hh];
          const ushort8_t vv = *(const ushort8_t*)(vb + (size_t)c * OUT_DIM + loff);
          #pragma unroll
          for (int x = 0; x < 8; ++x) acc[x] = fmaf(e, bf2f(vv[x]), acc[x]);
        }
      }
    } else {
      // -------- fallback: deg > SEGCAP, scores via global (never hit here)
      float m_run = -1e30f;
      for (int base = start; base < end; base += 64) {
        const int cnt = min(64, end - base);
        const int myc = (l < cnt) ? colsorted[base + l] : 0;
        for (int u = 0; u < cnt; ++u) {
          const int c = __shfl(myc, u);
          const ushort8_t kv = *(const ushort8_t*)(kb + (size_t)c * OUT_DIM + loff);
          float s = 0.f;
          #pragma unroll
          for (int x = 0; x < 8; ++x) s = fmaf(qf[x], bf2f(kv[x]), s);
          s += __shfl_xor(s, 1); s += __shfl_xor(s, 2); s += __shfl_xor(s, 4);
          m_run = fmaxf(m_run, s);
          if (j == 0) gscores[(size_t)(base + u) * NHEAD + hh] = s;
        }
      }
      float dsum = 0.f;
      for (int e = start + j; e < end; e += 8)
        dsum += __expf(gscores[(size_t)e * NHEAD + hh] - m_run);
      dsum += __shfl_xor(dsum, 1);
      dsum += __shfl_xor(dsum, 2);
      dsum += __shfl_xor(dsum, 4);
      inv = 1.0f / dsum;
      for (int base = start; base < end; base += 64) {
        const int cnt = min(64, end - base);
        const int myc = (l < cnt) ? colsorted[base + l] : 0;
        for (int u = 0; u < cnt; ++u) {
          const int c = __shfl(myc, u);
          const float e = __expf(gscores[(size_t)(base + u) * NHEAD + hh] - m_run);
          const ushort8_t vv = *(const ushort8_t*)(vb + (size_t)c * OUT_DIM + loff);
          #pragma unroll
          for (int x = 0; x < 8; ++x) acc[x] = fmaf(e, bf2f(vv[x]), acc[x]);
        }
      }
    }
  }

  // out natural [N][D][H]: lane holds head hh, dims dg..dg+7
  #pragma unroll
  for (int x = 0; x < 8; ++x)
    out[(size_t)wid * OUT_DIM + (size_t)(dg + x) * NHEAD + hh] = acc[x] * inv;
}

// ---------------- launch ----------------
extern "C" void kernel_launch(void* const* d_in, const int* in_sizes, int n_in,
                              void* d_out, int out_size, void* d_ws, size_t ws_size,
                              hipStream_t stream) {
  const float* Hm = (const float*)d_in[0];
  const float* Wq = (const float*)d_in[1];
  const float* bq = (const float*)d_in[2];
  const float* Wk = (const float*)d_in[3];
  const float* bk = (const float*)d_in[4];
  const float* Wv = (const float*)d_in[5];
  const float* bv = (const float*)d_in[6];
  const int* row  = (const int*)d_in[7];
  const int* col  = (const int*)d_in[8];
  float* out = (float*)d_out;

  const int Nn = in_sizes[0] / IN_DIM;               // 50000
  const int E  = in_sizes[7];                        // 1600000
  const int mtiles = (Nn + BM - 1) / BM;             // 391
  const int Mpad = mtiles * BM;                      // 50048
  const int nb = (Nn + 255) / 256;                   // scan blocks (196)

  // workspace carve-up (all 16B-aligned)
  unsigned short* hb  = (unsigned short*)d_ws;               // [Mpad][512] bf16
  unsigned short* Wt  = hb + (size_t)Mpad * IN_DIM;          // [1536][512] bf16 (perm)
  unsigned short* qTb = Wt + (size_t)3 * 512 * IN_DIM;       // [N][H*64] bf16
  unsigned short* kTb = qTb + (size_t)Nn * OUT_DIM;
  unsigned short* vTb = kTb + (size_t)Nn * OUT_DIM;
  float* gscores  = (float*)(vTb + (size_t)Nn * OUT_DIM);    // [E][8] fallback only
  int* counts     = (int*)(gscores + (size_t)E * NHEAD);
  int* offsets    = counts + Nn;                             // N+1
  int* cursor     = offsets + Nn + 1;
  int* colsorted  = cursor + Nn;                             // E
  int* bsums      = colsorted + E;                           // nb (<=1024)

  hipMemsetAsync(counts, 0, (size_t)Nn * sizeof(int), stream);
  hist_kernel<<<(E + 255) / 256, 256, 0, stream>>>(row, counts, E);
  scan_partial<<<nb, 256, 0, stream>>>(counts, bsums, Nn);
  scan_bsums<<<1, 1024, 0, stream>>>(bsums, nb);
  scan_final<<<nb, 256, 0, stream>>>(counts, bsums, offsets, cursor, Nn, E);
  scatter_kernel<<<(E + 255) / 256, 256, 0, stream>>>(row, col, cursor, colsorted, E);

  const int hblocks = (int)(((size_t)Mpad * IN_DIM / 8 + 255) / 256);
  convert_h<<<hblocks, 256, 0, stream>>>(Hm, hb, Nn);
  convert_w<<<dim3(8, 8, 3), 256, 0, stream>>>(Wq, Wk, Wv, Wt);

  qkv_gemm_mfma<<<dim3(mtiles, 4), 256, 0, stream>>>(hb, Wt, bq, bk, bv,
                                                     qTb, kTb, vTb, Nn);

  const size_t node_threads = (size_t)Nn * 64;
  fused_attn<<<(int)((node_threads + 255) / 256), 256, 0, stream>>>(
      qTb, kTb, vTb, colsorted, offsets, gscores, out, Nn);
}

// Round 7
// 1049.001 us; speedup vs baseline: 2.1891x; 1.0004x over previous
//
#include <hip/hip_runtime.h>
#include <hip/hip_bf16.h>
#include <math.h>

// Sparse multi-head attention (GAT-style). N=50000, E=1.6M, IN=OUT=512, H=8, D=64.
// q/k/v bf16 in [N][H*64] rows (1KB contiguous). Round 6: fused_attn sorts each
// segment's col indices in-register (bitonic over 64 lanes x 2 regs) so
// co-resident waves sweep col-space in lockstep -> k/v gathers become
// L2-band-local instead of random over 102 MB.

#define IN_DIM 512
#define OUT_DIM 512
#define NHEAD 8
#define HDIM 64
#define BM 128
#define BN 128
#define BK 32
#define SEGCAP 128
#define PADCOL 0x7fffffff

typedef short bf16x8 __attribute__((ext_vector_type(8)));
typedef float f32x4 __attribute__((ext_vector_type(4)));
typedef unsigned short ushort8_t __attribute__((ext_vector_type(8)));

__device__ __forceinline__ unsigned short f2bf(float f) {
  union { float f; unsigned int u; } v; v.f = f;
  unsigned int u = v.u;
  u = (u + 0x7FFF + ((u >> 16) & 1)) >> 16;   // RNE
  return (unsigned short)u;
}
__device__ __forceinline__ float bf2f(unsigned short s) {
  union { unsigned int u; float f; } v; v.u = ((unsigned int)s) << 16;
  return v.f;
}
__device__ __forceinline__ void gload_lds16(const void* g, void* l) {
  __builtin_amdgcn_global_load_lds(
      (const __attribute__((address_space(1))) unsigned int*)g,
      (__attribute__((address_space(3))) unsigned int*)l, 16, 0, 0);
}

// ---------------- fp32 -> bf16 converts ----------------
__global__ __launch_bounds__(256) void convert_h(const float* __restrict__ Hm,
                                                 unsigned short* __restrict__ hb,
                                                 int Nn) {
  const size_t base = ((size_t)blockIdx.x * blockDim.x + threadIdx.x) * 8;
  const int row = (int)(base >> 9);
  ushort8_t o = {0,0,0,0,0,0,0,0};
  if (row < Nn) {
    const float4 a = *(const float4*)(Hm + base);
    const float4 b = *(const float4*)(Hm + base + 4);
    o[0]=f2bf(a.x); o[1]=f2bf(a.y); o[2]=f2bf(a.z); o[3]=f2bf(a.w);
    o[4]=f2bf(b.x); o[5]=f2bf(b.y); o[6]=f2bf(b.z); o[7]=f2bf(b.w);
  }
  *(ushort8_t*)(hb + base) = o;
}

// Wt[mat*512 + perm(n)][k] = W_mat[k][n], bf16, perm(n) = (n&7)*64 + (n>>3).
__global__ __launch_bounds__(256) void convert_w(const float* __restrict__ Wq,
                                                 const float* __restrict__ Wk,
                                                 const float* __restrict__ Wv,
                                                 unsigned short* __restrict__ Wt) {
  __shared__ unsigned short tile[64][72];
  const int mat = blockIdx.z;
  const float* W = (mat == 0) ? Wq : (mat == 1) ? Wk : Wv;
  const int k0 = blockIdx.x * 64, n0 = blockIdx.y * 64;
  const int tid = threadIdx.x;
  const int r = tid >> 2, cb = (tid & 3) * 16;
  #pragma unroll
  for (int x = 0; x < 16; x += 4) {
    const float4 f = *(const float4*)(W + (size_t)(k0 + r) * OUT_DIM + n0 + cb + x);
    tile[cb + x + 0][r] = f2bf(f.x);
    tile[cb + x + 1][r] = f2bf(f.y);
    tile[cb + x + 2][r] = f2bf(f.z);
    tile[cb + x + 3][r] = f2bf(f.w);
  }
  __syncthreads();
  ushort8_t o1, o2;
  #pragma unroll
  for (int x = 0; x < 8; ++x) { o1[x] = tile[r][cb + x]; o2[x] = tile[r][cb + 8 + x]; }
  const int n = n0 + r;
  const int np = ((n & 7) << 6) | (n >> 3);      // permuted output column
  unsigned short* dst = Wt + (size_t)(mat * 512 + np) * IN_DIM + k0 + cb;
  *(ushort8_t*)(dst) = o1;
  *(ushort8_t*)(dst + 8) = o2;
}

// ---------------- MFMA bf16 GEMM: [Mpad,512] x [512,512] x 3 mats ----------
__global__ __launch_bounds__(256, 2) void qkv_gemm_mfma(
    const unsigned short* __restrict__ hb,   // [Mpad][512] bf16 (zero tail)
    const unsigned short* __restrict__ Wt,   // [3*512][512] bf16 (W^T, permuted)
    const float* __restrict__ bq, const float* __restrict__ bk, const float* __restrict__ bv,
    unsigned short* __restrict__ qTb, unsigned short* __restrict__ kTb,
    unsigned short* __restrict__ vTb, int Nn) {
  __shared__ __align__(16) unsigned short As[BM * BK];
  __shared__ __align__(16) unsigned short Bs[BN * BK];
  const int tid = threadIdx.x;
  const int l = tid & 63;
  const int w = tid >> 6;
  const int wr = w >> 1, wc = w & 1;          // wave -> 64x64 quadrant
  const int row0 = blockIdx.x * BM;
  const int col0 = blockIdx.y * BN;           // 0..511 (permuted col space)

  const int kcl = tid & 3;                    // 16B chunk slot within BK
  const int rl0 = tid >> 2;                   // tile-local row for issue 0

  for (int mat = 0; mat < 3; ++mat) {
    const unsigned short* Bsrc = Wt + (size_t)(mat * 512 + col0) * IN_DIM;
    f32x4 acc[4][4];
    const f32x4 zero = {0.f, 0.f, 0.f, 0.f};
    #pragma unroll
    for (int m = 0; m < 4; ++m)
      #pragma unroll
      for (int n = 0; n < 4; ++n) acc[m][n] = zero;

    for (int k0 = 0; k0 < IN_DIM; k0 += BK) {
      __syncthreads();
      #pragma unroll
      for (int t = 0; t < 2; ++t) {
        const int rl = rl0 + t * 64;
        const int kk = (kcl ^ ((rl >> 1) & 3)) * 8;   // pre-swizzled global source
        gload_lds16(hb + (size_t)(row0 + rl) * IN_DIM + k0 + kk,
                    (char*)As + t * 4096 + w * 1024);
        gload_lds16(Bsrc + (size_t)rl * IN_DIM + k0 + kk,
                    (char*)Bs + t * 4096 + w * 1024);
      }
      __syncthreads();   // drains vmcnt(0): LDS tiles ready
      bf16x8 af[4], bfr[4];
      #pragma unroll
      for (int m = 0; m < 4; ++m) {
        const int row = wr * 64 + m * 16 + (l & 15);
        const int kc = (l >> 4) ^ ((row >> 1) & 3);
        af[m] = *(const bf16x8*)&As[row * BK + kc * 8];
      }
      #pragma unroll
      for (int n = 0; n < 4; ++n) {
        const int row = wc * 64 + n * 16 + (l & 15);
        const int kc = (l >> 4) ^ ((row >> 1) & 3);
        bfr[n] = *(const bf16x8*)&Bs[row * BK + kc * 8];
      }
      #pragma unroll
      for (int m = 0; m < 4; ++m)
        #pragma unroll
        for (int n = 0; n < 4; ++n)
          acc[m][n] = __builtin_amdgcn_mfma_f32_16x16x32_bf16(af[m], bfr[n], acc[m][n], 0, 0, 0);
    }

    // epilogue: rows contiguous in [N][512] (= [N][H][64]); coalesced stores.
    const float scale = (mat == 0) ? 0.125f : 1.0f;     // D^-0.5 on q
    const float* bias = (mat == 0) ? bq : (mat == 1) ? bk : bv;
    unsigned short* dst = (mat == 0) ? qTb : (mat == 1) ? kTb : vTb;
    #pragma unroll
    for (int n = 0; n < 4; ++n) {
      const int cc = col0 + wc * 64 + n * 16 + (l & 15);  // permuted col 0..511
      const int o = ((cc & 63) << 3) | (cc >> 6);         // original col for bias
      const float bsv = bias[o];
      #pragma unroll
      for (int m = 0; m < 4; ++m) {
        #pragma unroll
        for (int j = 0; j < 4; ++j) {
          const int r = row0 + wr * 64 + m * 16 + (l >> 4) * 4 + j;
          if (r < Nn) dst[(size_t)r * OUT_DIM + cc] = f2bf((acc[m][n][j] + bsv) * scale);
        }
      }
    }
  }
}

// ---------------- CSR build ----------------
__global__ void hist_kernel(const int* __restrict__ row, int* __restrict__ counts, int E_) {
  const int i = blockIdx.x * blockDim.x + threadIdx.x;
  if (i < E_) atomicAdd(&counts[row[i]], 1);
}

// 3-stage scan: per-block reduce -> 1-block scan of block sums -> rescan+add.
__global__ __launch_bounds__(256) void scan_partial(const int* __restrict__ counts,
                                                    int* __restrict__ bsums, int n) {
  __shared__ int red[256];
  const int t = threadIdx.x;
  const int i = blockIdx.x * 256 + t;
  red[t] = (i < n) ? counts[i] : 0;
  __syncthreads();
  #pragma unroll
  for (int off = 128; off > 0; off >>= 1) {
    if (t < off) red[t] += red[t + off];
    __syncthreads();
  }
  if (t == 0) bsums[blockIdx.x] = red[0];
}

__global__ __launch_bounds__(1024) void scan_bsums(int* __restrict__ bsums, int nb) {
  __shared__ int lds[1024];
  const int t = threadIdx.x;
  const int v = (t < nb) ? bsums[t] : 0;
  lds[t] = v;
  __syncthreads();
  for (int off = 1; off < 1024; off <<= 1) {
    const int add = (t >= off) ? lds[t - off] : 0;
    __syncthreads();
    lds[t] += add;
    __syncthreads();
  }
  if (t < nb) bsums[t] = lds[t] - v;   // exclusive
}

__global__ __launch_bounds__(256) void scan_final(const int* __restrict__ counts,
                                                  const int* __restrict__ bsums,
                                                  int* __restrict__ offsets,
                                                  int* __restrict__ cursor,
                                                  int n, int E_) {
  __shared__ int lds[256];
  const int t = threadIdx.x;
  const int i = blockIdx.x * 256 + t;
  const int c = (i < n) ? counts[i] : 0;
  lds[t] = c;
  __syncthreads();
  for (int off = 1; off < 256; off <<= 1) {
    const int add = (t >= off) ? lds[t - off] : 0;
    __syncthreads();
    lds[t] += add;
    __syncthreads();
  }
  if (i < n) {
    const int ex = lds[t] - c + bsums[blockIdx.x];
    offsets[i] = ex;
    cursor[i] = ex;
  }
  if (blockIdx.x == 0 && t == 0) offsets[n] = E_;
}

__global__ void scatter_kernel(const int* __restrict__ row, const int* __restrict__ col,
                               int* __restrict__ cursor, int* __restrict__ colsorted, int E_) {
  const int i = blockIdx.x * blockDim.x + threadIdx.x;
  if (i < E_) {
    const int pos = atomicAdd(&cursor[row[i]], 1);
    colsorted[pos] = col[i];
  }
}

// ---------------- fused bsddmm + segment-softmax + spmm --------------------
// One wave per dst node. Lane l: head hh=l>>3, chunk j=l&7. Segment col
// indices are bitonic-sorted in-register first: all co-resident waves then
// walk col-space low->high in lockstep, so the active k/v gather band stays
// L2-resident instead of random over 102 MB.
__global__ __launch_bounds__(256) void fused_attn(
    const unsigned short* __restrict__ qb, const unsigned short* __restrict__ kb,
    const unsigned short* __restrict__ vb,
    const int* __restrict__ colsorted, const int* __restrict__ offsets,
    float* __restrict__ gscores,     // fallback only
    float* __restrict__ out, int Nn) {
  __shared__ float slds_all[4][SEGCAP * NHEAD];   // 16 KB
  const int wid = (int)((blockIdx.x * (size_t)blockDim.x + threadIdx.x) >> 6);
  if (wid >= Nn) return;
  const int l = threadIdx.x & 63;
  const int hh = l >> 3, j = l & 7;
  const int start = offsets[wid], end = offsets[wid + 1];
  const int seg = end - start;
  const size_t loff = (size_t)l * 8;
  const int dg = (l & 7) * 8;

  float acc[8];
  #pragma unroll
  for (int x = 0; x < 8; ++x) acc[x] = 0.f;
  float inv = 0.f;                      // seg==0 -> write zeros

  if (seg > 0) {
    const ushort8_t q8 = *(const ushort8_t*)(qb + (size_t)wid * OUT_DIM + loff);
    float qf[8];
    #pragma unroll
    for (int x = 0; x < 8; ++x) qf[x] = bf2f(q8[x]);

    if (seg <= SEGCAP) {
      float* slds = slds_all[threadIdx.x >> 6];
      int myc0 = (l < seg) ? colsorted[start + l] : PADCOL;
      int myc1 = (64 + l < seg) ? colsorted[start + 64 + l] : PADCOL;

      // ---- in-register bitonic sort of the segment's cols (pads -> end)
      if (seg <= 64) {
        // 64-element bitonic on myc0 (element index == lane)
        #pragma unroll
        for (int k = 2; k <= 64; k <<= 1) {
          #pragma unroll
          for (int jj = k >> 1; jj > 0; jj >>= 1) {
            const int p = __shfl_xor(myc0, jj);
            const bool keepmin = (((l & jj) == 0) == ((l & k) == 0));
            myc0 = keepmin ? min(myc0, p) : max(myc0, p);
          }
        }
      } else {
        // 128-element bitonic: element i = r*64 + l (r = reg index)
        #pragma unroll
        for (int k = 2; k <= 32; k <<= 1) {
          #pragma unroll
          for (int jj = k >> 1; jj > 0; jj >>= 1) {
            const int p0 = __shfl_xor(myc0, jj);
            const int p1 = __shfl_xor(myc1, jj);
            const bool keepmin = (((l & jj) == 0) == ((l & k) == 0));
            myc0 = keepmin ? min(myc0, p0) : max(myc0, p0);
            myc1 = keepmin ? min(myc1, p1) : max(myc1, p1);
          }
        }
        // k = 64 stage: reg0 ascending, reg1 descending (i&64 differs)
        #pragma unroll
        for (int jj = 32; jj > 0; jj >>= 1) {
          const int p0 = __shfl_xor(myc0, jj);
          const int p1 = __shfl_xor(myc1, jj);
          const bool lo = ((l & jj) == 0);
          myc0 = lo ? min(myc0, p0) : max(myc0, p0);
          myc1 = lo ? max(myc1, p1) : min(myc1, p1);
        }
        // k = 128 final merge: j=64 is the cross-reg exchange, then both asc
        {
          const int a = min(myc0, myc1), b = max(myc0, myc1);
          myc0 = a; myc1 = b;
        }
        #pragma unroll
        for (int jj = 32; jj > 0; jj >>= 1) {
          const int p0 = __shfl_xor(myc0, jj);
          const int p1 = __shfl_xor(myc1, jj);
          const bool lo = ((l & jj) == 0);
          myc0 = lo ? min(myc0, p0) : max(myc0, p0);
          myc1 = lo ? min(myc1, p1) : max(myc1, p1);
        }
      }

      float m_run = -1e30f;

      // ---- k-phase: scores -> LDS, online max
      #pragma unroll
      for (int chunk = 0; chunk < 2; ++chunk) {
        const int base = chunk * 64;
        if (base >= seg) break;
        const int cnt = min(64, seg - base);
        const int myc = chunk ? myc1 : myc0;
        int u = 0;
        for (; u + 4 <= cnt; u += 4) {
          const int c0 = __shfl(myc, u + 0);
          const int c1 = __shfl(myc, u + 1);
          const int c2 = __shfl(myc, u + 2);
          const int c3 = __shfl(myc, u + 3);
          const ushort8_t ka = *(const ushort8_t*)(kb + (size_t)c0 * OUT_DIM + loff);
          const ushort8_t kb1 = *(const ushort8_t*)(kb + (size_t)c1 * OUT_DIM + loff);
          const ushort8_t kc = *(const ushort8_t*)(kb + (size_t)c2 * OUT_DIM + loff);
          const ushort8_t kd = *(const ushort8_t*)(kb + (size_t)c3 * OUT_DIM + loff);
          float s0 = 0.f, s1 = 0.f, s2 = 0.f, s3 = 0.f;
          #pragma unroll
          for (int x = 0; x < 8; ++x) {
            s0 = fmaf(qf[x], bf2f(ka[x]), s0);
            s1 = fmaf(qf[x], bf2f(kb1[x]), s1);
            s2 = fmaf(qf[x], bf2f(kc[x]), s2);
            s3 = fmaf(qf[x], bf2f(kd[x]), s3);
          }
          s0 += __shfl_xor(s0, 1); s0 += __shfl_xor(s0, 2); s0 += __shfl_xor(s0, 4);
          s1 += __shfl_xor(s1, 1); s1 += __shfl_xor(s1, 2); s1 += __shfl_xor(s1, 4);
          s2 += __shfl_xor(s2, 1); s2 += __shfl_xor(s2, 2); s2 += __shfl_xor(s2, 4);
          s3 += __shfl_xor(s3, 1); s3 += __shfl_xor(s3, 2); s3 += __shfl_xor(s3, 4);
          m_run = fmaxf(m_run, fmaxf(fmaxf(s0, s1), fmaxf(s2, s3)));
          if (j == 0) {
            slds[(base + u + 0) * NHEAD + hh] = s0;
            slds[(base + u + 1) * NHEAD + hh] = s1;
            slds[(base + u + 2) * NHEAD + hh] = s2;
            slds[(base + u + 3) * NHEAD + hh] = s3;
          }
        }
        for (; u < cnt; ++u) {
          const int c = __shfl(myc, u);
          const ushort8_t kv = *(const ushort8_t*)(kb + (size_t)c * OUT_DIM + loff);
          float s = 0.f;
          #pragma unroll
          for (int x = 0; x < 8; ++x) s = fmaf(qf[x], bf2f(kv[x]), s);
          s += __shfl_xor(s, 1); s += __shfl_xor(s, 2); s += __shfl_xor(s, 4);
          m_run = fmaxf(m_run, s);
          if (j == 0) slds[(base + u) * NHEAD + hh] = s;
        }
      }
      // m_run is group-uniform (post-butterfly scores are identical in-group)
      __builtin_amdgcn_wave_barrier();

      // ---- denom pass: s -> ex in place, per-head sum
      float dsum = 0.f;
      for (int u = j; u < seg; u += 8) {
        const float ex = __expf(slds[u * NHEAD + hh] - m_run);
        slds[u * NHEAD + hh] = ex;
        dsum += ex;
      }
      dsum += __shfl_xor(dsum, 1);
      dsum += __shfl_xor(dsum, 2);
      dsum += __shfl_xor(dsum, 4);
      inv = 1.0f / dsum;
      __builtin_amdgcn_wave_barrier();

      // ---- v-phase: acc += ex * v[col]
      #pragma unroll
      for (int chunk = 0; chunk < 2; ++chunk) {
        const int base = chunk * 64;
        if (base >= seg) break;
        const int cnt = min(64, seg - base);
        const int myc = chunk ? myc1 : myc0;
        int u = 0;
        for (; u + 4 <= cnt; u += 4) {
          const int c0 = __shfl(myc, u + 0);
          const int c1 = __shfl(myc, u + 1);
          const int c2 = __shfl(myc, u + 2);
          const int c3 = __shfl(myc, u + 3);
          const float e0 = slds[(base + u + 0) * NHEAD + hh];
          const float e1 = slds[(base + u + 1) * NHEAD + hh];
          const float e2 = slds[(base + u + 2) * NHEAD + hh];
          const float e3 = slds[(base + u + 3) * NHEAD + hh];
          const ushort8_t va = *(const ushort8_t*)(vb + (size_t)c0 * OUT_DIM + loff);
          const ushort8_t vb1 = *(const ushort8_t*)(vb + (size_t)c1 * OUT_DIM + loff);
          const ushort8_t vc = *(const ushort8_t*)(vb + (size_t)c2 * OUT_DIM + loff);
          const ushort8_t vd = *(const ushort8_t*)(vb + (size_t)c3 * OUT_DIM + loff);
          #pragma unroll
          for (int x = 0; x < 8; ++x) {
            acc[x] = fmaf(e0, bf2f(va[x]), acc[x]);
            acc[x] = fmaf(e1, bf2f(vb1[x]), acc[x]);
            acc[x] = fmaf(e2, bf2f(vc[x]), acc[x]);
            acc[x] = fmaf(e3, bf2f(vd[x]), acc[x]);
          }
        }
        for (; u < cnt; ++u) {
          const int c = __shfl(myc, u);
          const float e = slds[(base + u) * NHEAD + hh];
          const ushort8_t vv = *(const ushort8_t*)(vb + (size_t)c * OUT_DIM + loff);
          #pragma unroll
          for (int x = 0; x < 8; ++x) acc[x] = fmaf(e, bf2f(vv[x]), acc[x]);
        }
      }
    } else {
      // -------- fallback: deg > SEGCAP, scores via global (never hit here)
      float m_run = -1e30f;
      for (int base = start; base < end; base += 64) {
        const int cnt = min(64, end - base);
        const int myc = (l < cnt) ? colsorted[base + l] : 0;
        for (int u = 0; u < cnt; ++u) {
          const int c = __shfl(myc, u);
          const ushort8_t kv = *(const ushort8_t*)(kb + (size_t)c * OUT_DIM + loff);
          float s = 0.f;
          #pragma unroll
          for (int x = 0; x < 8; ++x) s = fmaf(qf[x], bf2f(kv[x]), s);
          s += __shfl_xor(s, 1); s += __shfl_xor(s, 2); s += __shfl_xor(s, 4);
          m_run = fmaxf(m_run, s);
          if (j == 0) gscores[(size_t)(base + u) * NHEAD + hh] = s;
        }
      }
      float dsum = 0.f;
      for (int e = start + j; e < end; e += 8)
        dsum += __expf(gscores[(size_t)e * NHEAD + hh] - m_run);
      dsum += __shfl_xor(dsum, 1);
      dsum += __shfl_xor(dsum, 2);
      dsum += __shfl_xor(dsum, 4);
      inv = 1.0f / dsum;
      for (int base = start; base < end; base += 64) {
        const int cnt = min(64, end - base);
        const int myc = (l < cnt) ? colsorted[base + l] : 0;
        for (int u = 0; u < cnt; ++u) {
          const int c = __shfl(myc, u);
          const float e = __expf(gscores[(size_t)(base + u) * NHEAD + hh] - m_run);
          const ushort8_t vv = *(const ushort8_t*)(vb + (size_t)c * OUT_DIM + loff);
          #pragma unroll
          for (int x = 0; x < 8; ++x) acc[x] = fmaf(e, bf2f(vv[x]), acc[x]);
        }
      }
    }
  }

  // out natural [N][D][H]: lane holds head hh, dims dg..dg+7
  #pragma unroll
  for (int x = 0; x < 8; ++x)
    out[(size_t)wid * OUT_DIM + (size_t)(dg + x) * NHEAD + hh] = acc[x] * inv;
}

// ---------------- launch ----------------
extern "C" void kernel_launch(void* const* d_in, const int* in_sizes, int n_in,
                              void* d_out, int out_size, void* d_ws, size_t ws_size,
                              hipStream_t stream) {
  const float* Hm = (const float*)d_in[0];
  const float* Wq = (const float*)d_in[1];
  const float* bq = (const float*)d_in[2];
  const float* Wk = (const float*)d_in[3];
  const float* bk = (const float*)d_in[4];
  const float* Wv = (const float*)d_in[5];
  const float* bv = (const float*)d_in[6];
  const int* row  = (const int*)d_in[7];
  const int* col  = (const int*)d_in[8];
  float* out = (float*)d_out;

  const int Nn = in_sizes[0] / IN_DIM;               // 50000
  const int E  = in_sizes[7];                        // 1600000
  const int mtiles = (Nn + BM - 1) / BM;             // 391
  const int Mpad = mtiles * BM;                      // 50048
  const int nb = (Nn + 255) / 256;                   // scan blocks (196)

  // workspace carve-up (all 16B-aligned)
  unsigned short* hb  = (unsigned short*)d_ws;               // [Mpad][512] bf16
  unsigned short* Wt  = hb + (size_t)Mpad * IN_DIM;          // [1536][512] bf16 (perm)
  unsigned short* qTb = Wt + (size_t)3 * 512 * IN_DIM;       // [N][H*64] bf16
  unsigned short* kTb = qTb + (size_t)Nn * OUT_DIM;
  unsigned short* vTb = kTb + (size_t)Nn * OUT_DIM;
  float* gscores  = (float*)(vTb + (size_t)Nn * OUT_DIM);    // [E][8] fallback only
  int* counts     = (int*)(gscores + (size_t)E * NHEAD);
  int* offsets    = counts + Nn;                             // N+1
  int* cursor     = offsets + Nn + 1;
  int* colsorted  = cursor + Nn;                             // E
  int* bsums      = colsorted + E;                           // nb (<=1024)

  hipMemsetAsync(counts, 0, (size_t)Nn * sizeof(int), stream);
  hist_kernel<<<(E + 255) / 256, 256, 0, stream>>>(row, counts, E);
  scan_partial<<<nb, 256, 0, stream>>>(counts, bsums, Nn);
  scan_bsums<<<1, 1024, 0, stream>>>(bsums, nb);
  scan_final<<<nb, 256, 0, stream>>>(counts, bsums, offsets, cursor, Nn, E);
  scatter_kernel<<<(E + 255) / 256, 256, 0, stream>>>(row, col, cursor, colsorted, E);

  const int hblocks = (int)(((size_t)Mpad * IN_DIM / 8 + 255) / 256);
  convert_h<<<hblocks, 256, 0, stream>>>(Hm, hb, Nn);
  convert_w<<<dim3(8, 8, 3), 256, 0, stream>>>(Wq, Wk, Wv, Wt);

  qkv_gemm_mfma<<<dim3(mtiles, 4), 256, 0, stream>>>(hb, Wt, bq, bk, bv,
                                                     qTb, kTb, vTb, Nn);

  const size_t node_threads = (size_t)Nn * 64;
  fused_attn<<<(int)((node_threads + 255) / 256), 256, 0, stream>>>(
      qTb, kTb, vTb, colsorted, offsets, gscores, out, Nn);
}